// Round 16
// baseline (244.401 us; speedup 1.0000x reference)
//
#include <hip/hip_runtime.h>
#include <math.h>

// SpGraphAttentionLayer on MI355X — round 16.
// k5 occupancy fix: 128-node blocks (grid 392, acc[2][8], ~115 VGPR) and
// MS/DW aliased into ONE 33.8KB LDS buffer (MS dead before DW epilogue).
// Rest = round 15.

#define NHEAD 4

typedef unsigned short u16;
typedef __attribute__((ext_vector_type(4))) unsigned short u16x4;
typedef __attribute__((ext_vector_type(8))) unsigned short u16x8;
typedef __attribute__((ext_vector_type(8))) short bf16x8;
typedef __attribute__((ext_vector_type(4))) float f32x4;

__device__ __forceinline__ float bf2f(u16 v) {
    union { unsigned u; float f; } x; x.u = ((unsigned)v) << 16; return x.f;
}
__device__ __forceinline__ u16 f2bf(float f) {
    union { float f; unsigned u; } x; x.f = f;
    const unsigned r = x.u + 0x7FFFu + ((x.u >> 16) & 1u);
    return (u16)(r >> 16);
}

__global__ __launch_bounds__(256) void k1_prep(
    const float* __restrict__ proj, const float* __restrict__ W,
    const float* __restrict__ a, const float* __restrict__ hw,
    u16* __restrict__ M_bf,
    float* __restrict__ asrc, float* __restrict__ atgt, float* __restrict__ arel,
    u16* __restrict__ WcatT_bf, float* __restrict__ wsoft,
    float* __restrict__ orth_part)
{
    __shared__ float projS[128*132];
    __shared__ float WS[32*132];
    __shared__ float tS[128];
    __shared__ float red[256];
    const int h = blockIdx.x;
    const int part = blockIdx.y;
    const int z = blockIdx.z;
    const int tid = threadIdx.x;
    if (part < 2 && z >= 4) return;
    const float* projH = proj + h*(128*128);
    const float* WH = W + h*(128*320);
    const float* aH = a + h*128;

    {
        const float4* p4 = (const float4*)projH;
        for (int idx = tid; idx < 4096; idx += 256)
            *(float4*)&projS[(idx>>5)*132 + (idx&31)*4] = p4[idx];
    }

    if (part < 2) {
        const int koff = part ? 128 : 0;
        for (int idx = tid; idx < 1024; idx += 256) {
            const int ol = idx>>5, jq = idx&31;
            *(float4*)&WS[ol*132 + jq*4] = *(const float4*)&WH[(z*32+ol)*320 + koff + jq*4];
        }
        __syncthreads();
        u16* Mout = M_bf + ((size_t)(part*4 + h))*16384;
        for (int idx = tid; idx < 1024; idx += 256) {
            const int ol = idx>>5, jq = idx&31;
            float4 acc; acc.x=0.f; acc.y=0.f; acc.z=0.f; acc.w=0.f;
            for (int i = 0; i < 128; ++i) {
                const float wv = WS[ol*132 + i];
                const float4 pv = *(const float4*)&projS[i*132 + jq*4];
                acc.x += wv*pv.x; acc.y += wv*pv.y; acc.z += wv*pv.z; acc.w += wv*pv.w;
            }
            u16x4 pk; pk.x=f2bf(acc.x); pk.y=f2bf(acc.y); pk.z=f2bf(acc.z); pk.w=f2bf(acc.w);
            *(u16x4*)&Mout[(z*32+ol)*128 + jq*4] = pk;
        }
        if (z == 0) {
            if (tid < 128) {
                float s = 0.f;
                for (int o = 0; o < 128; ++o) s += aH[o]*WH[o*320 + koff + tid];
                tS[tid] = s;
            }
            __syncthreads();
            if (tid < 128) {
                float s = 0.f;
                for (int i = 0; i < 128; ++i) s += tS[i]*projS[i*132 + tid];
                (part ? atgt : asrc)[h*128 + tid] = s;
            }
        }
    } else {
        __syncthreads();
        float local = 0.f;
        const int base = z*2048;
        for (int idx = base + tid; idx < base + 2048; idx += 256) {
            const int i = idx>>7, k = idx&127;
            if (i > k) continue;
            float s = 0.f;
            for (int q = 0; q < 32; ++q) {
                const float4 pi = *(const float4*)&projS[i*132 + q*4];
                const float4 pk = *(const float4*)&projS[k*132 + q*4];
                s += pi.x*pk.x + pi.y*pk.y + pi.z*pk.z + pi.w*pk.w;
            }
            if (i == k) { s -= 1.f; local += s*s; }
            else local += 2.f*s*s;
        }
        red[tid] = local;
        __syncthreads();
        for (int st = 128; st > 0; st >>= 1) {
            if (tid < st) red[tid] += red[tid+st];
            __syncthreads();
        }
        if (tid == 0) atomicAdd(&orth_part[h], red[0]);
        if (z == 0) {
            if (tid < 64) {
                float s = 0.f;
                for (int o = 0; o < 128; ++o) s += aH[o]*WH[o*320 + 256 + tid];
                arel[h*64 + tid] = s;
            }
            for (int idx = tid; idx < 8192; idx += 256) {
                const int r = idx & 63, o = idx >> 6;
                WcatT_bf[(size_t)o*256 + h*64 + r] = f2bf(WH[o*320 + 256 + r]);
            }
            if (h == 0 && tid == 0) {
                const float m = fmaxf(fmaxf(hw[0],hw[1]), fmaxf(hw[2],hw[3]));
                const float e0=expf(hw[0]-m), e1=expf(hw[1]-m), e2=expf(hw[2]-m), e3=expf(hw[3]-m);
                const float s = e0+e1+e2+e3;
                wsoft[0]=e0/s; wsoft[1]=e1/s; wsoft[2]=e2/s; wsoft[3]=e3/s;
            }
        }
    }
}

// fused: input -> bf16 + per-node score partials + degree histogram (edge domain)
__global__ __launch_bounds__(256) void k0_nodes(
    const float* __restrict__ input, const float* __restrict__ asrc, const float* __restrict__ atgt,
    const int* __restrict__ edge, const int* __restrict__ nhop,
    u16* __restrict__ in_bf, float* __restrict__ s_src, float* __restrict__ s_tgt,
    int* __restrict__ deg, int N, int E1, int E2)
{
    __shared__ float aS[512], tS[512];
    const int tid = threadIdx.x;
    for (int idx = tid; idx < 512; idx += 256) { aS[idx] = asrc[idx]; tS[idx] = atgt[idx]; }
    const int t = blockIdx.x*256 + tid;
    if (t < E1 + E2) {
        const int src = (t < E1) ? edge[t] : nhop[t-E1];
        atomicAdd(&deg[src], 1);
    }
    __syncthreads();
    const int n = t;
    if (n >= N) return;
    const float4* inr = (const float4*)(input + (size_t)n*128);
    u16* ob = in_bf + (size_t)n*128;
    float ss[4] = {0.f,0.f,0.f,0.f}, st[4] = {0.f,0.f,0.f,0.f};
    for (int q = 0; q < 32; ++q) {
        const float4 v = inr[q];
        u16x4 pk; pk.x=f2bf(v.x); pk.y=f2bf(v.y); pk.z=f2bf(v.z); pk.w=f2bf(v.w);
        *(u16x4*)(ob + q*4) = pk;
        #pragma unroll
        for (int hh = 0; hh < 4; ++hh) {
            const float4 av = *(const float4*)&aS[hh*128 + q*4];
            const float4 tv = *(const float4*)&tS[hh*128 + q*4];
            ss[hh] += v.x*av.x + v.y*av.y + v.z*av.z + v.w*av.w;
            st[hh] += v.x*tv.x + v.y*tv.y + v.z*tv.z + v.w*tv.w;
        }
    }
    float4 o1; o1.x=ss[0]; o1.y=ss[1]; o1.z=ss[2]; o1.w=ss[3];
    float4 o2; o2.x=st[0]; o2.y=st[1]; o2.z=st[2]; o2.w=st[3];
    *(float4*)(s_src + (size_t)n*4) = o1;
    *(float4*)(s_tgt + (size_t)n*4) = o2;
}

// Swapped-operand MFMA GEMM, tgt matrices only (mats 4..7 of M_bf).
__global__ __launch_bounds__(256) void k2_mfma(
    const u16* __restrict__ in_bf, const u16* __restrict__ M_bf,
    u16* __restrict__ tbl, int N)
{
    __shared__ u16 MS[16384];
    __shared__ u16 DW[4][16*136];
    const int tid = threadIdx.x;
    const int w = tid >> 6, lane = tid & 63;
    const int bid = blockIdx.x;
    const int chunk = gridDim.x >> 3;
    const int swz = (bid & 7)*chunk + (bid >> 3);
    const int n0 = (swz >> 2)*256;
    const int mat = swz & 3;
    const int m = lane & 15, kg = lane >> 4;

    {
        const u16* Mp = M_bf + (size_t)(4 + mat)*16384;   // tgt matrices
        for (int c = tid; c < 2048; c += 256) {
            const int row = c >> 4, c16 = c & 15;
            const u16x8 v = *(const u16x8*)(Mp + row*128 + c16*8);
            *(u16x8*)((char*)MS + row*256 + ((c16*16) ^ ((row&7)<<4))) = v;
        }
    }
    __syncthreads();

    bf16x8 fa[8][4];
    #pragma unroll
    for (int nt = 0; nt < 8; ++nt) {
        const int row = nt*16 + m;
        #pragma unroll
        for (int ks = 0; ks < 4; ++ks) {
            const int c16 = ks*4 + kg;
            fa[nt][ks] = *(const bf16x8*)((const char*)MS + row*256 + ((c16*16) ^ ((row&7)<<4)));
        }
    }

    for (int sub = 0; sub < 4; ++sub) {
        const int nrow = n0 + w*64 + sub*16 + m;
        const int nclamp = (nrow < N) ? nrow : (N-1);
        bf16x8 fb[4];
        #pragma unroll
        for (int ks = 0; ks < 4; ++ks)
            fb[ks] = *(const bf16x8*)(in_bf + (size_t)nclamp*128 + ks*32 + kg*8);
        f32x4 acc[8];
        #pragma unroll
        for (int nt = 0; nt < 8; ++nt) { acc[nt][0]=0.f; acc[nt][1]=0.f; acc[nt][2]=0.f; acc[nt][3]=0.f; }
        #pragma unroll
        for (int nt = 0; nt < 8; ++nt)
            #pragma unroll
            for (int ks = 0; ks < 4; ++ks)
                acc[nt] = __builtin_amdgcn_mfma_f32_16x16x32_bf16(fa[nt][ks], fb[ks], acc[nt], 0, 0, 0);
        #pragma unroll
        for (int nt = 0; nt < 8; ++nt) {
            unsigned lo, hi;
            asm("v_cvt_pk_bf16_f32 %0, %1, %2" : "=v"(lo) : "v"(acc[nt][0]), "v"(acc[nt][1]));
            asm("v_cvt_pk_bf16_f32 %0, %1, %2" : "=v"(hi) : "v"(acc[nt][2]), "v"(acc[nt][3]));
            uint2 pk; pk.x = lo; pk.y = hi;
            *(uint2*)&DW[w][m*136 + nt*16 + kg*4] = pk;
        }
        const int nb = n0 + w*64 + sub*16;
        #pragma unroll
        for (int k = 0; k < 4; ++k) {
            const int idx = lane + k*64;
            const int row = idx >> 4, seg = idx & 15;
            const int n = nb + row;
            if (n < N) {
                const bf16x8 v = *(const bf16x8*)&DW[w][row*136 + seg*8];
                *(bf16x8*)(tbl + (size_t)n*512 + mat*128 + seg*8) = v;
            }
        }
    }
}

// scanA with scanB folded in via last-block-done lookback (nb <= 64).
__global__ __launch_bounds__(1024) void k_scanA(const int* __restrict__ deg, int* __restrict__ offsets,
                                                int* __restrict__ bsum, int* __restrict__ boff,
                                                int* __restrict__ sdone, int N, int nb)
{
    __shared__ int wsumS[16];
    __shared__ int ticketS;
    const int tid = threadIdx.x;
    const int lane = tid & 63, wid = tid >> 6;
    const int i0 = blockIdx.x*4096 + tid*4;
    int a0=0,a1=0,a2=0,a3=0;
    if (i0 + 3 < N) { const int4 t = *(const int4*)(deg + i0); a0=t.x; a1=t.y; a2=t.z; a3=t.w; }
    else { if (i0 < N) a0=deg[i0]; if (i0+1 < N) a1=deg[i0+1]; if (i0+2 < N) a2=deg[i0+2]; }
    const int s1=a0+a1, s2=s1+a2, s3=s2+a3;
    int s = s3;
    #pragma unroll
    for (int d = 1; d < 64; d <<= 1) { const int t = __shfl_up(s, d); if (lane >= d) s += t; }
    if (lane == 63) wsumS[wid] = s;
    __syncthreads();
    if (tid < 16) {
        int t = wsumS[tid];
        #pragma unroll
        for (int d = 1; d < 16; d <<= 1) { const int u = __shfl_up(t, d); if (tid >= d) t += u; }
        wsumS[tid] = t;
    }
    __syncthreads();
    const int ex = (wid ? wsumS[wid-1] : 0) + s - s3;
    if (i0 < N)     offsets[i0]   = ex;
    if (i0+1 < N)   offsets[i0+1] = ex + a0;
    if (i0+2 < N)   offsets[i0+2] = ex + s1;
    if (i0+3 < N)   offsets[i0+3] = ex + s2;
    if (tid == 0) {
        bsum[blockIdx.x] = wsumS[15];
        __threadfence();
        ticketS = atomicAdd(sdone, 1);
    }
    __syncthreads();
    if (ticketS == nb - 1 && tid < 64) {
        const int v = (tid < nb) ? atomicAdd(&bsum[tid], 0) : 0;
        int sv = v;
        #pragma unroll
        for (int d = 1; d < 64; d <<= 1) { const int t = __shfl_up(sv, d); if (tid >= d) sv += t; }
        if (tid < nb) boff[tid] = sv - v;
        if (tid == 63) offsets[N] = sv;
    }
}

// 3-phase fused edge pass.
__global__ __launch_bounds__(256) void k_fill2(
    const int* __restrict__ edge, const int* __restrict__ nhop,
    const float* __restrict__ emb1, const float* __restrict__ emb2,
    const float* __restrict__ s_src, const float* __restrict__ s_tgt,
    const float* __restrict__ arel,
    const int* __restrict__ offsets, const int* __restrict__ boff, int* __restrict__ cursor,
    int* __restrict__ csr_tgt, float* __restrict__ ee_perm, u16* __restrict__ emb_perm,
    int E1, int E2)
{
    __shared__ u16 embS[256*64];
    __shared__ float scS[256][4];
    __shared__ int pS[256];
    const int tid = threadIdx.x;
    const int g = tid >> 4, l = tid & 15;
    const int E = E1 + E2;
    const int ebase = blockIdx.x*256;

    {
        const float4 ar0 = *(const float4*)(arel + 0*64 + l*4);
        const float4 ar1 = *(const float4*)(arel + 1*64 + l*4);
        const float4 ar2 = *(const float4*)(arel + 2*64 + l*4);
        const float4 ar3 = *(const float4*)(arel + 3*64 + l*4);
        #pragma unroll 4
        for (int it = 0; it < 16; ++it) {
            const int el = it*16 + g;
            const int e = ebase + el;
            if (e >= E) continue;
            const float4 v = (e < E1) ? *(const float4*)(emb1 + (size_t)e*64 + l*4)
                                      : *(const float4*)(emb2 + (size_t)(e-E1)*64 + l*4);
            u16x4 pk; pk.x=f2bf(v.x); pk.y=f2bf(v.y); pk.z=f2bf(v.z); pk.w=f2bf(v.w);
            *(u16x4*)&embS[el*64 + l*4] = pk;
            float p0 = v.x*ar0.x + v.y*ar0.y + v.z*ar0.z + v.w*ar0.w;
            float p1 = v.x*ar1.x + v.y*ar1.y + v.z*ar1.z + v.w*ar1.w;
            float p2 = v.x*ar2.x + v.y*ar2.y + v.z*ar2.z + v.w*ar2.w;
            float p3 = v.x*ar3.x + v.y*ar3.y + v.z*ar3.z + v.w*ar3.w;
            #pragma unroll
            for (int d = 1; d < 16; d <<= 1) {
                p0 += __shfl_xor(p0, d);
                p1 += __shfl_xor(p1, d);
                p2 += __shfl_xor(p2, d);
                p3 += __shfl_xor(p3, d);
            }
            if (l == 0) {
                float4 sc; sc.x=p0; sc.y=p1; sc.z=p2; sc.w=p3;
                *(float4*)&scS[el][0] = sc;
            }
        }
    }
    __syncthreads();

    {
        const int e = ebase + tid;
        if (e < E) {
            int src, tgt;
            if (e < E1) { src = edge[e]; tgt = edge[E1+e]; }
            else { const int e2 = e-E1; src = nhop[e2]; tgt = nhop[E2+e2]; }
            const float4 s4 = *(const float4*)(s_src + (size_t)src*4);
            const float4 t4 = *(const float4*)(s_tgt + (size_t)tgt*4);
            const float4 pr = *(const float4*)&scS[tid][0];
            float4 eo;
            { const float sc = s4.x+t4.x+pr.x; eo.x = expf(sc>0.f ? -sc : -0.2f*sc); }
            { const float sc = s4.y+t4.y+pr.y; eo.y = expf(sc>0.f ? -sc : -0.2f*sc); }
            { const float sc = s4.z+t4.z+pr.z; eo.z = expf(sc>0.f ? -sc : -0.2f*sc); }
            { const float sc = s4.w+t4.w+pr.w; eo.w = expf(sc>0.f ? -sc : -0.2f*sc); }
            const int pos = atomicAdd(&cursor[src], 1);
            const int p = offsets[src] + boff[src>>12] + pos;
            csr_tgt[p] = tgt;
            *(float4*)(ee_perm + (size_t)p*4) = eo;
            pS[tid] = p;
        }
    }
    __syncthreads();

    #pragma unroll 4
    for (int it = 0; it < 16; ++it) {
        const int el = it*16 + g;
        const int e = ebase + el;
        if (e >= E) continue;
        const int p = pS[el];
        const u16x4 pk = *(const u16x4*)&embS[el*64 + l*4];
        *(u16x4*)(emb_perm + (size_t)p*64 + l*4) = pk;
    }
}

// per-node wave gather: depth-4 guarded pipeline + LDS metadata broadcast.
__global__ __launch_bounds__(256) void k4_gather(
    const float* __restrict__ ee_perm, const int* __restrict__ offsets, const int* __restrict__ boff,
    const int* __restrict__ csr_tgt,
    const u16* __restrict__ emb_perm, const u16* __restrict__ tbl,
    const float* __restrict__ wsoft,
    u16* __restrict__ pout_bf, u16* __restrict__ semb_bf, float* __restrict__ rowsum4,
    int N)
{
    __shared__ float eeS[4][64][4];
    __shared__ int   tgS[4][64];
    const int lane = threadIdx.x & 63;
    const int wv = threadIdx.x >> 6;
    const int n = blockIdx.x*4 + wv;
    if (n >= N) return;
    const int hl = lane >> 4;
    const int hoff = hl*128 + (lane & 15)*8;

    union HT { u16x8 v; unsigned u[4]; };

    float acc[8];
    #pragma unroll
    for (int j = 0; j < 8; ++j) acc[j] = 0.f;
    float sm0=0.f, sm1=0.f, sm2=0.f, sm3=0.f;
    float rsl0=0.f, rsl1=0.f, rsl2=0.f, rsl3=0.f;

    const int start = offsets[n] + boff[n>>12];
    const int end = (n+1 == N) ? offsets[N] : (offsets[n+1] + boff[(n+1)>>12]);
    for (int cb = start; cb < end; cb += 64) {
        const int rem = end - cb;
        const int cnt = rem < 64 ? rem : 64;    // wave-uniform
        int tgtL = 0;
        float4 eeL; eeL.x=0.f; eeL.y=0.f; eeL.z=0.f; eeL.w=0.f;
        if (lane < cnt) {
            tgtL = csr_tgt[cb + lane];
            eeL  = *(const float4*)(ee_perm + (size_t)(cb + lane)*4);
        }
        rsl0 += eeL.x; rsl1 += eeL.y; rsl2 += eeL.z; rsl3 += eeL.w;
        *(float4*)&eeS[wv][lane][0] = eeL;
        tgS[wv][lane] = tgtL;
        const int cp = (cnt + 3) & ~3;

        HT zz; zz.u[0]=0u; zz.u[1]=0u; zz.u[2]=0u; zz.u[3]=0u;
        HT ht0=zz, ht1=zz, ht2=zz, ht3=zz;
        u16 em0=0, em1=0, em2=0, em3=0;
#define K4_FETCH(J, IDX) { const int tg_ = tgS[wv][IDX]; \
            ht##J.v = *(const u16x8*)(tbl + (size_t)tg_*512 + hoff); \
            em##J = emb_perm[(size_t)(cb + (IDX))*64 + lane]; }
        if (0 < cnt) K4_FETCH(0, 0)
        if (1 < cnt) K4_FETCH(1, 1)
        if (2 < cnt) K4_FETCH(2, 2)
        if (3 < cnt) K4_FETCH(3, 3)

#define K4_STAGE(J) { \
            const float4 ee4 = *(const float4*)&eeS[wv][i+J][0]; \
            const float eh = eeS[wv][i+J][hl]; \
            _Pragma("unroll") \
            for (int p = 0; p < 4; ++p) { \
                union{unsigned u; float f;} lo_, hi_; \
                lo_.u = ht##J.u[p] << 16; hi_.u = ht##J.u[p] & 0xffff0000u; \
                acc[2*p]   += eh*lo_.f; \
                acc[2*p+1] += eh*hi_.f; \
            } \
            const float ev = bf2f(em##J); \
            sm0 += ee4.x*ev; sm1 += ee4.y*ev; sm2 += ee4.z*ev; sm3 += ee4.w*ev; \
            { const int ii = i + 4 + J; if (ii < cnt) K4_FETCH(J, ii) } }

        for (int i = 0; i < cp; i += 4) {
            K4_STAGE(0)
            K4_STAGE(1)
            K4_STAGE(2)
            K4_STAGE(3)
        }
#undef K4_STAGE
#undef K4_FETCH
    }

    #pragma unroll
    for (int d = 1; d < 64; d <<= 1) {
        rsl0 += __shfl_xor(rsl0, d);
        rsl1 += __shfl_xor(rsl1, d);
        rsl2 += __shfl_xor(rsl2, d);
        rsl3 += __shfl_xor(rsl3, d);
    }
    if (lane == 0) {
        float4 r4; r4.x=rsl0; r4.y=rsl1; r4.z=rsl2; r4.w=rsl3;
        *(float4*)(rowsum4 + (size_t)n*4) = r4;
    }

    const float4 ws4 = *(const float4*)wsoft;
    const float wh = (hl==0)?ws4.x:(hl==1)?ws4.y:(hl==2)?ws4.z:ws4.w;
    float p[8];
    #pragma unroll
    for (int j = 0; j < 8; ++j) {
        float pv = wh*acc[j];
        pv += __shfl_xor(pv, 16);
        pv += __shfl_xor(pv, 32);
        p[j] = pv;
    }
    if (hl == 0) {
        u16 pk[8];
        #pragma unroll
        for (int j = 0; j < 8; ++j) pk[j] = f2bf(p[j]);
        *(u16x8*)(pout_bf + (size_t)n*128 + (lane & 15)*8) = *(u16x8*)pk;
    }
    u16* so = semb_bf + (size_t)n*256;
    so[lane]       = f2bf(ws4.x*sm0);
    so[64 + lane]  = f2bf(ws4.y*sm1);
    so[128 + lane] = f2bf(ws4.z*sm2);
    so[192 + lane] = f2bf(ws4.w*sm3);
}

// K=768 MFMA GEMM, 128 nodes/block, MS/DW aliased (33.8KB LDS total).
__global__ __launch_bounds__(256) void k5_gemm(
    const u16* __restrict__ semb_bf, const u16* __restrict__ wcatT_bf,
    const u16* __restrict__ M_bf, const u16* __restrict__ in_bf,
    const u16* __restrict__ pout_bf,
    const float* __restrict__ rowsum4, const float* __restrict__ wsoft,
    const float* __restrict__ orth_part,
    float* __restrict__ out, int N)
{
    __shared__ __align__(16) char smemU[4*16*132*4];   // 33792B: MS (32KB) / DW alias
    u16* MS = (u16*)smemU;
    float* DWbase = (float*)smemU;
    const int tid = threadIdx.x;
    if (blockIdx.x == 0 && tid == 0)
        out[(size_t)N*128] = 0.01f*(sqrtf(orth_part[0])+sqrtf(orth_part[1])+sqrtf(orth_part[2])+sqrtf(orth_part[3]));
    const int w = tid >> 6, lane = tid & 63;
    const int m = lane & 15, kg = lane >> 4;
    const int n0 = blockIdx.x*128;

    const float4 ws4 = *(const float4*)wsoft;
    int rowS[2];
    float4 rhS[2];
    #pragma unroll
    for (int sub = 0; sub < 2; ++sub) {
        int r = n0 + w*32 + sub*16 + m; if (r >= N) r = N-1;
        rowS[sub] = r;
        const float4 rs = *(const float4*)(rowsum4 + (size_t)r*4);
        rhS[sub].x = ws4.x*rs.x; rhS[sub].y = ws4.y*rs.y;
        rhS[sub].z = ws4.z*rs.z; rhS[sub].w = ws4.w*rs.w;
    }

    f32x4 acc[2][8];
    #pragma unroll
    for (int sub = 0; sub < 2; ++sub)
        #pragma unroll
        for (int nt = 0; nt < 8; ++nt) { acc[sub][nt][0]=0.f; acc[sub][nt][1]=0.f; acc[sub][nt][2]=0.f; acc[sub][nt][3]=0.f; }

    // Phases 0-1: WcatT halves
    #pragma unroll
    for (int half = 0; half < 2; ++half) {
        __syncthreads();
        for (int c = tid; c < 2048; c += 256) {
            const int r = c >> 4, c16 = c & 15;
            const u16x8 v = *(const u16x8*)(wcatT_bf + (size_t)r*256 + half*128 + c16*8);
            *(u16x8*)((char*)MS + r*256 + ((c16*16) ^ ((r&7)<<4))) = v;
        }
        __syncthreads();
        #pragma unroll
        for (int sub = 0; sub < 2; ++sub) {
            bf16x8 fa[4];
            const u16* ap = semb_bf + (size_t)rowS[sub]*256 + half*128 + kg*8;
            #pragma unroll
            for (int ks = 0; ks < 4; ++ks) fa[ks] = *(const bf16x8*)(ap + ks*32);
            #pragma unroll
            for (int nt = 0; nt < 8; ++nt) {
                const int o = nt*16 + m;
                #pragma unroll
                for (int ks = 0; ks < 4; ++ks) {
                    const int c16 = ks*4 + kg;
                    const bf16x8 fb = *(const bf16x8*)((const char*)MS + o*256 + ((c16*16) ^ ((o&7)<<4)));
                    acc[sub][nt] = __builtin_amdgcn_mfma_f32_16x16x32_bf16(fa[ks], fb, acc[sub][nt], 0, 0, 0);
                }
            }
        }
    }

    // Phases 2-5: M_src[h]
    for (int h = 0; h < 4; ++h) {
        __syncthreads();
        {
            const u16* Mp = M_bf + (size_t)h*16384;
            for (int c = tid; c < 2048; c += 256) {
                const int r = c >> 4, c16 = c & 15;
                const u16x8 v = *(const u16x8*)(Mp + r*128 + c16*8);
                *(u16x8*)((char*)MS + r*256 + ((c16*16) ^ ((r&7)<<4))) = v;
            }
        }
        __syncthreads();
        #pragma unroll
        for (int sub = 0; sub < 2; ++sub) {
            const float rsc = (h==0)?rhS[sub].x:(h==1)?rhS[sub].y:(h==2)?rhS[sub].z:rhS[sub].w;
            union IU { bf16x8 v; unsigned u[4]; };
            bf16x8 fsc[4];
            const u16* ip = in_bf + (size_t)rowS[sub]*128 + kg*8;
            #pragma unroll
            for (int ks = 0; ks < 4; ++ks) {
                IU t; t.v = *(const bf16x8*)(ip + ks*32);
                IU o;
                #pragma unroll
                for (int p = 0; p < 4; ++p) {
                    union{unsigned u; float f;} lo_, hi_;
                    lo_.u = t.u[p] << 16; hi_.u = t.u[p] & 0xffff0000u;
                    const float a = lo_.f*rsc, b = hi_.f*rsc;
                    unsigned pk;
                    asm("v_cvt_pk_bf16_f32 %0, %1, %2" : "=v"(pk) : "v"(a), "v"(b));
                    o.u[p] = pk;
                }
                fsc[ks] = o.v;
            }
            #pragma unroll
            for (int nt = 0; nt < 8; ++nt) {
                const int o = nt*16 + m;
                #pragma unroll
                for (int ks = 0; ks < 4; ++ks) {
                    const int c16 = ks*4 + kg;
                    const bf16x8 fb = *(const bf16x8*)((const char*)MS + o*256 + ((c16*16) ^ ((o&7)<<4)));
                    acc[sub][nt] = __builtin_amdgcn_mfma_f32_16x16x32_bf16(fsc[ks], fb, acc[sub][nt], 0, 0, 0);
                }
            }
        }
    }

    // barrier before overwriting MS region with DW epilogue data
    __syncthreads();
    float* DW = DWbase + w*16*132;
    #pragma unroll
    for (int sub = 0; sub < 2; ++sub) {
        #pragma unroll
        for (int nt = 0; nt < 8; ++nt) {
            #pragma unroll
            for (int r = 0; r < 4; ++r)
                DW[(kg*4+r)*132 + nt*16 + m] = acc[sub][nt][r];
        }
        const int nb = n0 + w*32 + sub*16;
        #pragma unroll
        for (int k = 0; k < 8; ++k) {
            const int idx = lane + k*64;
            const int row = idx >> 5, q = idx & 31;
            const int n = nb + row;
            if (n < N) {
                const float4 d = *(const float4*)&DW[row*132 + q*4];
                const u16x4 pb = *(const u16x4*)(pout_bf + (size_t)n*128 + q*4);
                const float rinv = 1.0f / fmaxf(rowsum4[(size_t)n*4 + 3], 1e-12f);
                float v0 = (bf2f(pb.x) + d.x)*rinv;
                float v1 = (bf2f(pb.y) + d.y)*rinv;
                float v2 = (bf2f(pb.z) + d.z)*rinv;
                float v3 = (bf2f(pb.w) + d.w)*rinv;
                v0 = (v0 > 0.f) ? v0 : expm1f(v0);
                v1 = (v1 > 0.f) ? v1 : expm1f(v1);
                v2 = (v2 > 0.f) ? v2 : expm1f(v2);
                v3 = (v3 > 0.f) ? v3 : expm1f(v3);
                float4 r4; r4.x=v0; r4.y=v1; r4.z=v2; r4.w=v3;
                *(float4*)(out + (size_t)n*128 + q*4) = r4;
            }
        }
    }
}

extern "C" void kernel_launch(void* const* d_in, const int* in_sizes, int n_in,
                              void* d_out, int out_size, void* d_ws, size_t ws_size,
                              hipStream_t stream)
{
    const float* input = (const float*)d_in[0];
    const int*   edge  = (const int*)d_in[1];
    const float* emb1  = (const float*)d_in[2];
    const int*   nhop  = (const int*)d_in[3];
    const float* emb2  = (const float*)d_in[4];
    const float* proj  = (const float*)d_in[5];
    const float* W     = (const float*)d_in[6];
    const float* a     = (const float*)d_in[7];
    const float* hw    = (const float*)d_in[8];
    float* out = (float*)d_out;

    const int N  = in_sizes[0] / 128;
    const int E1 = in_sizes[1] / 2;
    const int E2 = in_sizes[3] / 2;
    const int E  = E1 + E2;
    (void)n_in; (void)out_size; (void)ws_size;

    char* wsb = (char*)d_ws;
    size_t off = 0;
    auto alloc = [&](size_t bytes) -> char* {
        char* p = wsb + off;
        off += (bytes + 255) & ~(size_t)255;
        return p;
    };
    u16*   in_bf    = (u16*)alloc((size_t)N*128*2);
    u16*   tbl      = (u16*)alloc((size_t)N*512*2);
    u16*   semb_bf  = (u16*)alloc((size_t)N*256*2);
    u16*   pout_bf  = (u16*)alloc((size_t)N*128*2);
    u16*   emb_perm = (u16*)alloc((size_t)E*64*2);
    float* ee_perm  = (float*)alloc((size_t)E*4*4);
    int*   csr_tgt  = (int*)alloc((size_t)E*4);
    u16*   M_bf     = (u16*)alloc((size_t)8*16384*2);
    u16*   WcatT_bf = (u16*)alloc((size_t)128*256*2);
    float* asrc     = (float*)alloc(512*4);
    float* atgt     = (float*)alloc(512*4);
    float* arel     = (float*)alloc(256*4);
    float* s_src    = (float*)alloc((size_t)N*4*4);
    float* s_tgt    = (float*)alloc((size_t)N*4*4);
    float* wsoft    = (float*)alloc(4*4);
    float* rowsum4  = (float*)alloc((size_t)N*4*4);
    int*   offsets  = (int*)alloc((size_t)(N+1)*4);
    int*   bsum     = (int*)alloc(64*4);
    int*   boff     = (int*)alloc(64*4);
    const size_t zoff0 = off;
    float* orth_part= (float*)alloc(4*4);
    int*   deg      = (int*)alloc((size_t)N*4);
    int*   cursor   = (int*)alloc((size_t)N*4);
    int*   sdone    = (int*)alloc(4);
    const size_t zoff1 = off;

    hipMemsetAsync(wsb + zoff0, 0, zoff1 - zoff0, stream);

    const int nbScan = (N + 4095) / 4096;
    const int nx = (N + 255) / 256;
    const int nx2 = (N + 127) / 128;
    const int nk0 = ((E > N ? E : N) + 255) / 256;

    k1_prep<<<dim3(NHEAD,3,8), dim3(256), 0, stream>>>(proj, W, a, hw, M_bf,
                                                       asrc, atgt, arel, WcatT_bf, wsoft, orth_part);
    k0_nodes<<<dim3(nk0), dim3(256), 0, stream>>>(input, asrc, atgt, edge, nhop,
                                                  in_bf, s_src, s_tgt, deg, N, E1, E2);
    k2_mfma<<<dim3(nx*4), dim3(256), 0, stream>>>(in_bf, M_bf, tbl, N);
    k_scanA<<<dim3(nbScan), dim3(1024), 0, stream>>>(deg, offsets, bsum, boff, sdone, N, nbScan);
    k_fill2<<<dim3((E+255)/256), dim3(256), 0, stream>>>(edge, nhop, emb1, emb2, s_src, s_tgt,
                                                         arel, offsets, boff, cursor,
                                                         csr_tgt, ee_perm, emb_perm, E1, E2);
    k4_gather<<<dim3((N+3)/4), dim3(256), 0, stream>>>(ee_perm, offsets, boff, csr_tgt, emb_perm,
                                                       tbl, wsoft, pout_bf, semb_bf, rowsum4, N);
    k5_gemm<<<dim3(nx2), dim3(256), 0, stream>>>(semb_bf, WcatT_bf, M_bf, in_bf, pout_bf,
                                                 rowsum4, wsoft, orth_part, out, N);
}

// Round 17
// 228.353 us; speedup vs baseline: 1.0703x; 1.0703x over previous
//
#include <hip/hip_runtime.h>
#include <math.h>

// SpGraphAttentionLayer on MI355X — round 17.
// k5's M_src staging phases removed: k2 computes BOTH tables again (hsrc_tbl for
// sequential use in k5, tbl/tgt for k4's random gather — stays 51MB for L3).
// k5 = 2 WcatT phases + epilogue that streams hsrc_tbl (rh-weighted sum).

#define NHEAD 4

typedef unsigned short u16;
typedef __attribute__((ext_vector_type(4))) unsigned short u16x4;
typedef __attribute__((ext_vector_type(8))) unsigned short u16x8;
typedef __attribute__((ext_vector_type(8))) short bf16x8;
typedef __attribute__((ext_vector_type(4))) float f32x4;

__device__ __forceinline__ float bf2f(u16 v) {
    union { unsigned u; float f; } x; x.u = ((unsigned)v) << 16; return x.f;
}
__device__ __forceinline__ u16 f2bf(float f) {
    union { float f; unsigned u; } x; x.f = f;
    const unsigned r = x.u + 0x7FFFu + ((x.u >> 16) & 1u);
    return (u16)(r >> 16);
}

__global__ __launch_bounds__(256) void k1_prep(
    const float* __restrict__ proj, const float* __restrict__ W,
    const float* __restrict__ a, const float* __restrict__ hw,
    u16* __restrict__ M_bf,
    float* __restrict__ asrc, float* __restrict__ atgt, float* __restrict__ arel,
    u16* __restrict__ WcatT_bf, float* __restrict__ wsoft,
    float* __restrict__ orth_part)
{
    __shared__ float projS[128*132];
    __shared__ float WS[32*132];
    __shared__ float tS[128];
    __shared__ float red[256];
    const int h = blockIdx.x;
    const int part = blockIdx.y;
    const int z = blockIdx.z;
    const int tid = threadIdx.x;
    if (part < 2 && z >= 4) return;
    const float* projH = proj + h*(128*128);
    const float* WH = W + h*(128*320);
    const float* aH = a + h*128;

    {
        const float4* p4 = (const float4*)projH;
        for (int idx = tid; idx < 4096; idx += 256)
            *(float4*)&projS[(idx>>5)*132 + (idx&31)*4] = p4[idx];
    }

    if (part < 2) {
        const int koff = part ? 128 : 0;
        for (int idx = tid; idx < 1024; idx += 256) {
            const int ol = idx>>5, jq = idx&31;
            *(float4*)&WS[ol*132 + jq*4] = *(const float4*)&WH[(z*32+ol)*320 + koff + jq*4];
        }
        __syncthreads();
        u16* Mout = M_bf + ((size_t)(part*4 + h))*16384;
        for (int idx = tid; idx < 1024; idx += 256) {
            const int ol = idx>>5, jq = idx&31;
            float4 acc; acc.x=0.f; acc.y=0.f; acc.z=0.f; acc.w=0.f;
            for (int i = 0; i < 128; ++i) {
                const float wv = WS[ol*132 + i];
                const float4 pv = *(const float4*)&projS[i*132 + jq*4];
                acc.x += wv*pv.x; acc.y += wv*pv.y; acc.z += wv*pv.z; acc.w += wv*pv.w;
            }
            u16x4 pk; pk.x=f2bf(acc.x); pk.y=f2bf(acc.y); pk.z=f2bf(acc.z); pk.w=f2bf(acc.w);
            *(u16x4*)&Mout[(z*32+ol)*128 + jq*4] = pk;
        }
        if (z == 0) {
            if (tid < 128) {
                float s = 0.f;
                for (int o = 0; o < 128; ++o) s += aH[o]*WH[o*320 + koff + tid];
                tS[tid] = s;
            }
            __syncthreads();
            if (tid < 128) {
                float s = 0.f;
                for (int i = 0; i < 128; ++i) s += tS[i]*projS[i*132 + tid];
                (part ? atgt : asrc)[h*128 + tid] = s;
            }
        }
    } else {
        __syncthreads();
        float local = 0.f;
        const int base = z*2048;
        for (int idx = base + tid; idx < base + 2048; idx += 256) {
            const int i = idx>>7, k = idx&127;
            if (i > k) continue;
            float s = 0.f;
            for (int q = 0; q < 32; ++q) {
                const float4 pi = *(const float4*)&projS[i*132 + q*4];
                const float4 pk = *(const float4*)&projS[k*132 + q*4];
                s += pi.x*pk.x + pi.y*pk.y + pi.z*pk.z + pi.w*pk.w;
            }
            if (i == k) { s -= 1.f; local += s*s; }
            else local += 2.f*s*s;
        }
        red[tid] = local;
        __syncthreads();
        for (int st = 128; st > 0; st >>= 1) {
            if (tid < st) red[tid] += red[tid+st];
            __syncthreads();
        }
        if (tid == 0) atomicAdd(&orth_part[h], red[0]);
        if (z == 0) {
            if (tid < 64) {
                float s = 0.f;
                for (int o = 0; o < 128; ++o) s += aH[o]*WH[o*320 + 256 + tid];
                arel[h*64 + tid] = s;
            }
            for (int idx = tid; idx < 8192; idx += 256) {
                const int r = idx & 63, o = idx >> 6;
                WcatT_bf[(size_t)o*256 + h*64 + r] = f2bf(WH[o*320 + 256 + r]);
            }
            if (h == 0 && tid == 0) {
                const float m = fmaxf(fmaxf(hw[0],hw[1]), fmaxf(hw[2],hw[3]));
                const float e0=expf(hw[0]-m), e1=expf(hw[1]-m), e2=expf(hw[2]-m), e3=expf(hw[3]-m);
                const float s = e0+e1+e2+e3;
                wsoft[0]=e0/s; wsoft[1]=e1/s; wsoft[2]=e2/s; wsoft[3]=e3/s;
            }
        }
    }
}

// fused: input -> bf16 + per-node score partials + degree histogram (edge domain)
__global__ __launch_bounds__(256) void k0_nodes(
    const float* __restrict__ input, const float* __restrict__ asrc, const float* __restrict__ atgt,
    const int* __restrict__ edge, const int* __restrict__ nhop,
    u16* __restrict__ in_bf, float* __restrict__ s_src, float* __restrict__ s_tgt,
    int* __restrict__ deg, int N, int E1, int E2)
{
    __shared__ float aS[512], tS[512];
    const int tid = threadIdx.x;
    for (int idx = tid; idx < 512; idx += 256) { aS[idx] = asrc[idx]; tS[idx] = atgt[idx]; }
    const int t = blockIdx.x*256 + tid;
    if (t < E1 + E2) {
        const int src = (t < E1) ? edge[t] : nhop[t-E1];
        atomicAdd(&deg[src], 1);
    }
    __syncthreads();
    const int n = t;
    if (n >= N) return;
    const float4* inr = (const float4*)(input + (size_t)n*128);
    u16* ob = in_bf + (size_t)n*128;
    float ss[4] = {0.f,0.f,0.f,0.f}, st[4] = {0.f,0.f,0.f,0.f};
    for (int q = 0; q < 32; ++q) {
        const float4 v = inr[q];
        u16x4 pk; pk.x=f2bf(v.x); pk.y=f2bf(v.y); pk.z=f2bf(v.z); pk.w=f2bf(v.w);
        *(u16x4*)(ob + q*4) = pk;
        #pragma unroll
        for (int hh = 0; hh < 4; ++hh) {
            const float4 av = *(const float4*)&aS[hh*128 + q*4];
            const float4 tv = *(const float4*)&tS[hh*128 + q*4];
            ss[hh] += v.x*av.x + v.y*av.y + v.z*av.z + v.w*av.w;
            st[hh] += v.x*tv.x + v.y*tv.y + v.z*tv.z + v.w*tv.w;
        }
    }
    float4 o1; o1.x=ss[0]; o1.y=ss[1]; o1.z=ss[2]; o1.w=ss[3];
    float4 o2; o2.x=st[0]; o2.y=st[1]; o2.z=st[2]; o2.w=st[3];
    *(float4*)(s_src + (size_t)n*4) = o1;
    *(float4*)(s_tgt + (size_t)n*4) = o2;
}

// Swapped-operand MFMA GEMM, all 8 matrices: mats 0-3 -> hsrc_tbl, 4-7 -> tbl.
__global__ __launch_bounds__(256) void k2_mfma(
    const u16* __restrict__ in_bf, const u16* __restrict__ M_bf,
    u16* __restrict__ hsrc_tbl, u16* __restrict__ tbl, int N)
{
    __shared__ u16 MS[16384];
    __shared__ u16 DW[4][16*136];
    const int tid = threadIdx.x;
    const int w = tid >> 6, lane = tid & 63;
    const int bid = blockIdx.x;
    const int chunk = gridDim.x >> 3;
    const int swz = (bid & 7)*chunk + (bid >> 3);
    const int n0 = (swz >> 3)*256;
    const int mat = swz & 7;
    const int m = lane & 15, kg = lane >> 4;

    {
        const u16* Mp = M_bf + (size_t)mat*16384;
        for (int c = tid; c < 2048; c += 256) {
            const int row = c >> 4, c16 = c & 15;
            const u16x8 v = *(const u16x8*)(Mp + row*128 + c16*8);
            *(u16x8*)((char*)MS + row*256 + ((c16*16) ^ ((row&7)<<4))) = v;
        }
    }
    __syncthreads();

    bf16x8 fa[8][4];
    #pragma unroll
    for (int nt = 0; nt < 8; ++nt) {
        const int row = nt*16 + m;
        #pragma unroll
        for (int ks = 0; ks < 4; ++ks) {
            const int c16 = ks*4 + kg;
            fa[nt][ks] = *(const bf16x8*)((const char*)MS + row*256 + ((c16*16) ^ ((row&7)<<4)));
        }
    }

    u16* outT = (mat < 4) ? (hsrc_tbl + mat*128) : (tbl + (mat-4)*128);

    for (int sub = 0; sub < 4; ++sub) {
        const int nrow = n0 + w*64 + sub*16 + m;
        const int nclamp = (nrow < N) ? nrow : (N-1);
        bf16x8 fb[4];
        #pragma unroll
        for (int ks = 0; ks < 4; ++ks)
            fb[ks] = *(const bf16x8*)(in_bf + (size_t)nclamp*128 + ks*32 + kg*8);
        f32x4 acc[8];
        #pragma unroll
        for (int nt = 0; nt < 8; ++nt) { acc[nt][0]=0.f; acc[nt][1]=0.f; acc[nt][2]=0.f; acc[nt][3]=0.f; }
        #pragma unroll
        for (int nt = 0; nt < 8; ++nt)
            #pragma unroll
            for (int ks = 0; ks < 4; ++ks)
                acc[nt] = __builtin_amdgcn_mfma_f32_16x16x32_bf16(fa[nt][ks], fb[ks], acc[nt], 0, 0, 0);
        #pragma unroll
        for (int nt = 0; nt < 8; ++nt) {
            unsigned lo, hi;
            asm("v_cvt_pk_bf16_f32 %0, %1, %2" : "=v"(lo) : "v"(acc[nt][0]), "v"(acc[nt][1]));
            asm("v_cvt_pk_bf16_f32 %0, %1, %2" : "=v"(hi) : "v"(acc[nt][2]), "v"(acc[nt][3]));
            uint2 pk; pk.x = lo; pk.y = hi;
            *(uint2*)&DW[w][m*136 + nt*16 + kg*4] = pk;
        }
        const int nb = n0 + w*64 + sub*16;
        #pragma unroll
        for (int k = 0; k < 4; ++k) {
            const int idx = lane + k*64;
            const int row = idx >> 4, seg = idx & 15;
            const int n = nb + row;
            if (n < N) {
                const bf16x8 v = *(const bf16x8*)&DW[w][row*136 + seg*8];
                *(bf16x8*)(outT + (size_t)n*512 + seg*8) = v;
            }
        }
    }
}

// scanA with scanB folded in via last-block-done lookback (nb <= 64).
__global__ __launch_bounds__(1024) void k_scanA(const int* __restrict__ deg, int* __restrict__ offsets,
                                                int* __restrict__ bsum, int* __restrict__ boff,
                                                int* __restrict__ sdone, int N, int nb)
{
    __shared__ int wsumS[16];
    __shared__ int ticketS;
    const int tid = threadIdx.x;
    const int lane = tid & 63, wid = tid >> 6;
    const int i0 = blockIdx.x*4096 + tid*4;
    int a0=0,a1=0,a2=0,a3=0;
    if (i0 + 3 < N) { const int4 t = *(const int4*)(deg + i0); a0=t.x; a1=t.y; a2=t.z; a3=t.w; }
    else { if (i0 < N) a0=deg[i0]; if (i0+1 < N) a1=deg[i0+1]; if (i0+2 < N) a2=deg[i0+2]; }
    const int s1=a0+a1, s2=s1+a2, s3=s2+a3;
    int s = s3;
    #pragma unroll
    for (int d = 1; d < 64; d <<= 1) { const int t = __shfl_up(s, d); if (lane >= d) s += t; }
    if (lane == 63) wsumS[wid] = s;
    __syncthreads();
    if (tid < 16) {
        int t = wsumS[tid];
        #pragma unroll
        for (int d = 1; d < 16; d <<= 1) { const int u = __shfl_up(t, d); if (tid >= d) t += u; }
        wsumS[tid] = t;
    }
    __syncthreads();
    const int ex = (wid ? wsumS[wid-1] : 0) + s - s3;
    if (i0 < N)     offsets[i0]   = ex;
    if (i0+1 < N)   offsets[i0+1] = ex + a0;
    if (i0+2 < N)   offsets[i0+2] = ex + s1;
    if (i0+3 < N)   offsets[i0+3] = ex + s2;
    if (tid == 0) {
        bsum[blockIdx.x] = wsumS[15];
        __threadfence();
        ticketS = atomicAdd(sdone, 1);
    }
    __syncthreads();
    if (ticketS == nb - 1 && tid < 64) {
        const int v = (tid < nb) ? atomicAdd(&bsum[tid], 0) : 0;
        int sv = v;
        #pragma unroll
        for (int d = 1; d < 64; d <<= 1) { const int t = __shfl_up(sv, d); if (tid >= d) sv += t; }
        if (tid < nb) boff[tid] = sv - v;
        if (tid == 63) offsets[N] = sv;
    }
}

// 3-phase fused edge pass.
__global__ __launch_bounds__(256) void k_fill2(
    const int* __restrict__ edge, const int* __restrict__ nhop,
    const float* __restrict__ emb1, const float* __restrict__ emb2,
    const float* __restrict__ s_src, const float* __restrict__ s_tgt,
    const float* __restrict__ arel,
    const int* __restrict__ offsets, const int* __restrict__ boff, int* __restrict__ cursor,
    int* __restrict__ csr_tgt, float* __restrict__ ee_perm, u16* __restrict__ emb_perm,
    int E1, int E2)
{
    __shared__ u16 embS[256*64];
    __shared__ float scS[256][4];
    __shared__ int pS[256];
    const int tid = threadIdx.x;
    const int g = tid >> 4, l = tid & 15;
    const int E = E1 + E2;
    const int ebase = blockIdx.x*256;

    {
        const float4 ar0 = *(const float4*)(arel + 0*64 + l*4);
        const float4 ar1 = *(const float4*)(arel + 1*64 + l*4);
        const float4 ar2 = *(const float4*)(arel + 2*64 + l*4);
        const float4 ar3 = *(const float4*)(arel + 3*64 + l*4);
        #pragma unroll 4
        for (int it = 0; it < 16; ++it) {
            const int el = it*16 + g;
            const int e = ebase + el;
            if (e >= E) continue;
            const float4 v = (e < E1) ? *(const float4*)(emb1 + (size_t)e*64 + l*4)
                                      : *(const float4*)(emb2 + (size_t)(e-E1)*64 + l*4);
            u16x4 pk; pk.x=f2bf(v.x); pk.y=f2bf(v.y); pk.z=f2bf(v.z); pk.w=f2bf(v.w);
            *(u16x4*)&embS[el*64 + l*4] = pk;
            float p0 = v.x*ar0.x + v.y*ar0.y + v.z*ar0.z + v.w*ar0.w;
            float p1 = v.x*ar1.x + v.y*ar1.y + v.z*ar1.z + v.w*ar1.w;
            float p2 = v.x*ar2.x + v.y*ar2.y + v.z*ar2.z + v.w*ar2.w;
            float p3 = v.x*ar3.x + v.y*ar3.y + v.z*ar3.z + v.w*ar3.w;
            #pragma unroll
            for (int d = 1; d < 16; d <<= 1) {
                p0 += __shfl_xor(p0, d);
                p1 += __shfl_xor(p1, d);
                p2 += __shfl_xor(p2, d);
                p3 += __shfl_xor(p3, d);
            }
            if (l == 0) {
                float4 sc; sc.x=p0; sc.y=p1; sc.z=p2; sc.w=p3;
                *(float4*)&scS[el][0] = sc;
            }
        }
    }
    __syncthreads();

    {
        const int e = ebase + tid;
        if (e < E) {
            int src, tgt;
            if (e < E1) { src = edge[e]; tgt = edge[E1+e]; }
            else { const int e2 = e-E1; src = nhop[e2]; tgt = nhop[E2+e2]; }
            const float4 s4 = *(const float4*)(s_src + (size_t)src*4);
            const float4 t4 = *(const float4*)(s_tgt + (size_t)tgt*4);
            const float4 pr = *(const float4*)&scS[tid][0];
            float4 eo;
            { const float sc = s4.x+t4.x+pr.x; eo.x = expf(sc>0.f ? -sc : -0.2f*sc); }
            { const float sc = s4.y+t4.y+pr.y; eo.y = expf(sc>0.f ? -sc : -0.2f*sc); }
            { const float sc = s4.z+t4.z+pr.z; eo.z = expf(sc>0.f ? -sc : -0.2f*sc); }
            { const float sc = s4.w+t4.w+pr.w; eo.w = expf(sc>0.f ? -sc : -0.2f*sc); }
            const int pos = atomicAdd(&cursor[src], 1);
            const int p = offsets[src] + boff[src>>12] + pos;
            csr_tgt[p] = tgt;
            *(float4*)(ee_perm + (size_t)p*4) = eo;
            pS[tid] = p;
        }
    }
    __syncthreads();

    #pragma unroll 4
    for (int it = 0; it < 16; ++it) {
        const int el = it*16 + g;
        const int e = ebase + el;
        if (e >= E) continue;
        const int p = pS[el];
        const u16x4 pk = *(const u16x4*)&embS[el*64 + l*4];
        *(u16x4*)(emb_perm + (size_t)p*64 + l*4) = pk;
    }
}

// per-node wave gather: depth-4 guarded pipeline + LDS metadata broadcast.
__global__ __launch_bounds__(256) void k4_gather(
    const float* __restrict__ ee_perm, const int* __restrict__ offsets, const int* __restrict__ boff,
    const int* __restrict__ csr_tgt,
    const u16* __restrict__ emb_perm, const u16* __restrict__ tbl,
    const float* __restrict__ wsoft,
    u16* __restrict__ pout_bf, u16* __restrict__ semb_bf, float* __restrict__ rowsum4,
    int N)
{
    __shared__ float eeS[4][64][4];
    __shared__ int   tgS[4][64];
    const int lane = threadIdx.x & 63;
    const int wv = threadIdx.x >> 6;
    const int n = blockIdx.x*4 + wv;
    if (n >= N) return;
    const int hl = lane >> 4;
    const int hoff = hl*128 + (lane & 15)*8;

    union HT { u16x8 v; unsigned u[4]; };

    float acc[8];
    #pragma unroll
    for (int j = 0; j < 8; ++j) acc[j] = 0.f;
    float sm0=0.f, sm1=0.f, sm2=0.f, sm3=0.f;
    float rsl0=0.f, rsl1=0.f, rsl2=0.f, rsl3=0.f;

    const int start = offsets[n] + boff[n>>12];
    const int end = (n+1 == N) ? offsets[N] : (offsets[n+1] + boff[(n+1)>>12]);
    for (int cb = start; cb < end; cb += 64) {
        const int rem = end - cb;
        const int cnt = rem < 64 ? rem : 64;    // wave-uniform
        int tgtL = 0;
        float4 eeL; eeL.x=0.f; eeL.y=0.f; eeL.z=0.f; eeL.w=0.f;
        if (lane < cnt) {
            tgtL = csr_tgt[cb + lane];
            eeL  = *(const float4*)(ee_perm + (size_t)(cb + lane)*4);
        }
        rsl0 += eeL.x; rsl1 += eeL.y; rsl2 += eeL.z; rsl3 += eeL.w;
        *(float4*)&eeS[wv][lane][0] = eeL;
        tgS[wv][lane] = tgtL;
        const int cp = (cnt + 3) & ~3;

        HT zz; zz.u[0]=0u; zz.u[1]=0u; zz.u[2]=0u; zz.u[3]=0u;
        HT ht0=zz, ht1=zz, ht2=zz, ht3=zz;
        u16 em0=0, em1=0, em2=0, em3=0;
#define K4_FETCH(J, IDX) { const int tg_ = tgS[wv][IDX]; \
            ht##J.v = *(const u16x8*)(tbl + (size_t)tg_*512 + hoff); \
            em##J = emb_perm[(size_t)(cb + (IDX))*64 + lane]; }
        if (0 < cnt) K4_FETCH(0, 0)
        if (1 < cnt) K4_FETCH(1, 1)
        if (2 < cnt) K4_FETCH(2, 2)
        if (3 < cnt) K4_FETCH(3, 3)

#define K4_STAGE(J) { \
            const float4 ee4 = *(const float4*)&eeS[wv][i+J][0]; \
            const float eh = eeS[wv][i+J][hl]; \
            _Pragma("unroll") \
            for (int p = 0; p < 4; ++p) { \
                union{unsigned u; float f;} lo_, hi_; \
                lo_.u = ht##J.u[p] << 16; hi_.u = ht##J.u[p] & 0xffff0000u; \
                acc[2*p]   += eh*lo_.f; \
                acc[2*p+1] += eh*hi_.f; \
            } \
            const float ev = bf2f(em##J); \
            sm0 += ee4.x*ev; sm1 += ee4.y*ev; sm2 += ee4.z*ev; sm3 += ee4.w*ev; \
            { const int ii = i + 4 + J; if (ii < cnt) K4_FETCH(J, ii) } }

        for (int i = 0; i < cp; i += 4) {
            K4_STAGE(0)
            K4_STAGE(1)
            K4_STAGE(2)
            K4_STAGE(3)
        }
#undef K4_STAGE
#undef K4_FETCH
    }

    #pragma unroll
    for (int d = 1; d < 64; d <<= 1) {
        rsl0 += __shfl_xor(rsl0, d);
        rsl1 += __shfl_xor(rsl1, d);
        rsl2 += __shfl_xor(rsl2, d);
        rsl3 += __shfl_xor(rsl3, d);
    }
    if (lane == 0) {
        float4 r4; r4.x=rsl0; r4.y=rsl1; r4.z=rsl2; r4.w=rsl3;
        *(float4*)(rowsum4 + (size_t)n*4) = r4;
    }

    const float4 ws4 = *(const float4*)wsoft;
    const float wh = (hl==0)?ws4.x:(hl==1)?ws4.y:(hl==2)?ws4.z:ws4.w;
    float p[8];
    #pragma unroll
    for (int j = 0; j < 8; ++j) {
        float pv = wh*acc[j];
        pv += __shfl_xor(pv, 16);
        pv += __shfl_xor(pv, 32);
        p[j] = pv;
    }
    if (hl == 0) {
        u16 pk[8];
        #pragma unroll
        for (int j = 0; j < 8; ++j) pk[j] = f2bf(p[j]);
        *(u16x8*)(pout_bf + (size_t)n*128 + (lane & 15)*8) = *(u16x8*)pk;
    }
    u16* so = semb_bf + (size_t)n*256;
    so[lane]       = f2bf(ws4.x*sm0);
    so[64 + lane]  = f2bf(ws4.y*sm1);
    so[128 + lane] = f2bf(ws4.z*sm2);
    so[192 + lane] = f2bf(ws4.w*sm3);
}

// k5: 2 WcatT staging phases + epilogue streaming hsrc_tbl (rh-weighted) + pout.
// 128 nodes/block, MS/DW aliased (33.8KB), acc[2][8].
__global__ __launch_bounds__(256) void k5_gemm(
    const u16* __restrict__ semb_bf, const u16* __restrict__ wcatT_bf,
    const u16* __restrict__ hsrc_tbl, const u16* __restrict__ pout_bf,
    const float* __restrict__ rowsum4, const float* __restrict__ wsoft,
    const float* __restrict__ orth_part,
    float* __restrict__ out, int N)
{
    __shared__ __align__(16) char smemU[4*16*132*4];   // 33792B: MS (32KB) / DW alias
    u16* MS = (u16*)smemU;
    float* DWbase = (float*)smemU;
    const int tid = threadIdx.x;
    if (blockIdx.x == 0 && tid == 0)
        out[(size_t)N*128] = 0.01f*(sqrtf(orth_part[0])+sqrtf(orth_part[1])+sqrtf(orth_part[2])+sqrtf(orth_part[3]));
    const int w = tid >> 6, lane = tid & 63;
    const int m = lane & 15, kg = lane >> 4;
    const int n0 = blockIdx.x*128;
    const float4 ws4 = *(const float4*)wsoft;

    int rowS[2];
    #pragma unroll
    for (int sub = 0; sub < 2; ++sub) {
        int r = n0 + w*32 + sub*16 + m; if (r >= N) r = N-1;
        rowS[sub] = r;
    }

    f32x4 acc[2][8];
    #pragma unroll
    for (int sub = 0; sub < 2; ++sub)
        #pragma unroll
        for (int nt = 0; nt < 8; ++nt) { acc[sub][nt][0]=0.f; acc[sub][nt][1]=0.f; acc[sub][nt][2]=0.f; acc[sub][nt][3]=0.f; }

    #pragma unroll
    for (int half = 0; half < 2; ++half) {
        __syncthreads();
        for (int c = tid; c < 2048; c += 256) {
            const int r = c >> 4, c16 = c & 15;
            const u16x8 v = *(const u16x8*)(wcatT_bf + (size_t)r*256 + half*128 + c16*8);
            *(u16x8*)((char*)MS + r*256 + ((c16*16) ^ ((r&7)<<4))) = v;
        }
        __syncthreads();
        #pragma unroll
        for (int sub = 0; sub < 2; ++sub) {
            bf16x8 fa[4];
            const u16* ap = semb_bf + (size_t)rowS[sub]*256 + half*128 + kg*8;
            #pragma unroll
            for (int ks = 0; ks < 4; ++ks) fa[ks] = *(const bf16x8*)(ap + ks*32);
            #pragma unroll
            for (int nt = 0; nt < 8; ++nt) {
                const int o = nt*16 + m;
                #pragma unroll
                for (int ks = 0; ks < 4; ++ks) {
                    const int c16 = ks*4 + kg;
                    const bf16x8 fb = *(const bf16x8*)((const char*)MS + o*256 + ((c16*16) ^ ((o&7)<<4)));
                    acc[sub][nt] = __builtin_amdgcn_mfma_f32_16x16x32_bf16(fa[ks], fb, acc[sub][nt], 0, 0, 0);
                }
            }
        }
    }

    // barrier before overwriting MS region with DW epilogue data
    __syncthreads();
    float* DW = DWbase + w*16*132;
    #pragma unroll
    for (int sub = 0; sub < 2; ++sub) {
        #pragma unroll
        for (int nt = 0; nt < 8; ++nt) {
            #pragma unroll
            for (int r = 0; r < 4; ++r)
                DW[(kg*4+r)*132 + nt*16 + m] = acc[sub][nt][r];
        }
        const int nb = n0 + w*32 + sub*16;
        #pragma unroll
        for (int k = 0; k < 8; ++k) {
            const int idx = lane + k*64;
            const int row = idx >> 5, q = idx & 31;
            const int n = nb + row;
            if (n < N) {
                const float4 d = *(const float4*)&DW[row*132 + q*4];
                const u16x4 pb = *(const u16x4*)(pout_bf + (size_t)n*128 + q*4);
                const float4 rs = *(const float4*)(rowsum4 + (size_t)n*4);
                const float rh0 = ws4.x*rs.x, rh1 = ws4.y*rs.y, rh2 = ws4.z*rs.z, rh3 = ws4.w*rs.w;
                const u16* hp = hsrc_tbl + (size_t)n*512 + q*4;
                const u16x4 h0 = *(const u16x4*)(hp);
                const u16x4 h1 = *(const u16x4*)(hp + 128);
                const u16x4 h2 = *(const u16x4*)(hp + 256);
                const u16x4 h3 = *(const u16x4*)(hp + 384);
                const float rinv = 1.0f / fmaxf(rs.w, 1e-12f);
                float v0 = (bf2f(pb.x) + d.x + rh0*bf2f(h0.x) + rh1*bf2f(h1.x) + rh2*bf2f(h2.x) + rh3*bf2f(h3.x))*rinv;
                float v1 = (bf2f(pb.y) + d.y + rh0*bf2f(h0.y) + rh1*bf2f(h1.y) + rh2*bf2f(h2.y) + rh3*bf2f(h3.y))*rinv;
                float v2 = (bf2f(pb.z) + d.z + rh0*bf2f(h0.z) + rh1*bf2f(h1.z) + rh2*bf2f(h2.z) + rh3*bf2f(h3.z))*rinv;
                float v3 = (bf2f(pb.w) + d.w + rh0*bf2f(h0.w) + rh1*bf2f(h1.w) + rh2*bf2f(h2.w) + rh3*bf2f(h3.w))*rinv;
                v0 = (v0 > 0.f) ? v0 : expm1f(v0);
                v1 = (v1 > 0.f) ? v1 : expm1f(v1);
                v2 = (v2 > 0.f) ? v2 : expm1f(v2);
                v3 = (v3 > 0.f) ? v3 : expm1f(v3);
                float4 r4; r4.x=v0; r4.y=v1; r4.z=v2; r4.w=v3;
                *(float4*)(out + (size_t)n*128 + q*4) = r4;
            }
        }
    }
}

extern "C" void kernel_launch(void* const* d_in, const int* in_sizes, int n_in,
                              void* d_out, int out_size, void* d_ws, size_t ws_size,
                              hipStream_t stream)
{
    const float* input = (const float*)d_in[0];
    const int*   edge  = (const int*)d_in[1];
    const float* emb1  = (const float*)d_in[2];
    const int*   nhop  = (const int*)d_in[3];
    const float* emb2  = (const float*)d_in[4];
    const float* proj  = (const float*)d_in[5];
    const float* W     = (const float*)d_in[6];
    const float* a     = (const float*)d_in[7];
    const float* hw    = (const float*)d_in[8];
    float* out = (float*)d_out;

    const int N  = in_sizes[0] / 128;
    const int E1 = in_sizes[1] / 2;
    const int E2 = in_sizes[3] / 2;
    const int E  = E1 + E2;
    (void)n_in; (void)out_size; (void)ws_size;

    char* wsb = (char*)d_ws;
    size_t off = 0;
    auto alloc = [&](size_t bytes) -> char* {
        char* p = wsb + off;
        off += (bytes + 255) & ~(size_t)255;
        return p;
    };
    u16*   in_bf    = (u16*)alloc((size_t)N*128*2);
    u16*   tbl      = (u16*)alloc((size_t)N*512*2);
    u16*   hsrc_tbl = (u16*)alloc((size_t)N*512*2);
    u16*   semb_bf  = (u16*)alloc((size_t)N*256*2);
    u16*   pout_bf  = (u16*)alloc((size_t)N*128*2);
    u16*   emb_perm = (u16*)alloc((size_t)E*64*2);
    float* ee_perm  = (float*)alloc((size_t)E*4*4);
    int*   csr_tgt  = (int*)alloc((size_t)E*4);
    u16*   M_bf     = (u16*)alloc((size_t)8*16384*2);
    u16*   WcatT_bf = (u16*)alloc((size_t)128*256*2);
    float* asrc     = (float*)alloc(512*4);
    float* atgt     = (float*)alloc(512*4);
    float* arel     = (float*)alloc(256*4);
    float* s_src    = (float*)alloc((size_t)N*4*4);
    float* s_tgt    = (float*)alloc((size_t)N*4*4);
    float* wsoft    = (float*)alloc(4*4);
    float* rowsum4  = (float*)alloc((size_t)N*4*4);
    int*   offsets  = (int*)alloc((size_t)(N+1)*4);
    int*   bsum     = (int*)alloc(64*4);
    int*   boff     = (int*)alloc(64*4);
    const size_t zoff0 = off;
    float* orth_part= (float*)alloc(4*4);
    int*   deg      = (int*)alloc((size_t)N*4);
    int*   cursor   = (int*)alloc((size_t)N*4);
    int*   sdone    = (int*)alloc(4);
    const size_t zoff1 = off;

    hipMemsetAsync(wsb + zoff0, 0, zoff1 - zoff0, stream);

    const int nbScan = (N + 4095) / 4096;
    const int nx = (N + 255) / 256;
    const int nx2 = (N + 127) / 128;
    const int nk0 = ((E > N ? E : N) + 255) / 256;

    k1_prep<<<dim3(NHEAD,3,8), dim3(256), 0, stream>>>(proj, W, a, hw, M_bf,
                                                       asrc, atgt, arel, WcatT_bf, wsoft, orth_part);
    k0_nodes<<<dim3(nk0), dim3(256), 0, stream>>>(input, asrc, atgt, edge, nhop,
                                                  in_bf, s_src, s_tgt, deg, N, E1, E2);
    k2_mfma<<<dim3(nx*8), dim3(256), 0, stream>>>(in_bf, M_bf, hsrc_tbl, tbl, N);
    k_scanA<<<dim3(nbScan), dim3(1024), 0, stream>>>(deg, offsets, bsum, boff, sdone, N, nbScan);
    k_fill2<<<dim3((E+255)/256), dim3(256), 0, stream>>>(edge, nhop, emb1, emb2, s_src, s_tgt,
                                                         arel, offsets, boff, cursor,
                                                         csr_tgt, ee_perm, emb_perm, E1, E2);
    k4_gather<<<dim3((N+3)/4), dim3(256), 0, stream>>>(ee_perm, offsets, boff, csr_tgt, emb_perm,
                                                       tbl, wsoft, pout_bf, semb_bf, rowsum4, N);
    k5_gemm<<<dim3(nx2), dim3(256), 0, stream>>>(semb_bf, WcatT_bf, hsrc_tbl, pout_bf,
                                                 rowsum4, wsoft, orth_part, out, N);
}

// Round 18
// 222.828 us; speedup vs baseline: 1.0968x; 1.0248x over previous
//
#include <hip/hip_runtime.h>
#include <math.h>

// SpGraphAttentionLayer on MI355X — round 18.
// Single change vs round 17: k4 is persistent (grid-stride over nodes, 3072
// blocks) while KEEPING the depth-4 pipeline (round 9 only ever tested
// grid-stride with depth-2). Amortizes per-block fixed costs; steadier
// wave residency for the latency-bound tbl gather.

#define NHEAD 4

typedef unsigned short u16;
typedef __attribute__((ext_vector_type(4))) unsigned short u16x4;
typedef __attribute__((ext_vector_type(8))) unsigned short u16x8;
typedef __attribute__((ext_vector_type(8))) short bf16x8;
typedef __attribute__((ext_vector_type(4))) float f32x4;

__device__ __forceinline__ float bf2f(u16 v) {
    union { unsigned u; float f; } x; x.u = ((unsigned)v) << 16; return x.f;
}
__device__ __forceinline__ u16 f2bf(float f) {
    union { float f; unsigned u; } x; x.f = f;
    const unsigned r = x.u + 0x7FFFu + ((x.u >> 16) & 1u);
    return (u16)(r >> 16);
}

__global__ __launch_bounds__(256) void k1_prep(
    const float* __restrict__ proj, const float* __restrict__ W,
    const float* __restrict__ a, const float* __restrict__ hw,
    u16* __restrict__ M_bf,
    float* __restrict__ asrc, float* __restrict__ atgt, float* __restrict__ arel,
    u16* __restrict__ WcatT_bf, float* __restrict__ wsoft,
    float* __restrict__ orth_part)
{
    __shared__ float projS[128*132];
    __shared__ float WS[32*132];
    __shared__ float tS[128];
    __shared__ float red[256];
    const int h = blockIdx.x;
    const int part = blockIdx.y;
    const int z = blockIdx.z;
    const int tid = threadIdx.x;
    if (part < 2 && z >= 4) return;
    const float* projH = proj + h*(128*128);
    const float* WH = W + h*(128*320);
    const float* aH = a + h*128;

    {
        const float4* p4 = (const float4*)projH;
        for (int idx = tid; idx < 4096; idx += 256)
            *(float4*)&projS[(idx>>5)*132 + (idx&31)*4] = p4[idx];
    }

    if (part < 2) {
        const int koff = part ? 128 : 0;
        for (int idx = tid; idx < 1024; idx += 256) {
            const int ol = idx>>5, jq = idx&31;
            *(float4*)&WS[ol*132 + jq*4] = *(const float4*)&WH[(z*32+ol)*320 + koff + jq*4];
        }
        __syncthreads();
        u16* Mout = M_bf + ((size_t)(part*4 + h))*16384;
        for (int idx = tid; idx < 1024; idx += 256) {
            const int ol = idx>>5, jq = idx&31;
            float4 acc; acc.x=0.f; acc.y=0.f; acc.z=0.f; acc.w=0.f;
            for (int i = 0; i < 128; ++i) {
                const float wv = WS[ol*132 + i];
                const float4 pv = *(const float4*)&projS[i*132 + jq*4];
                acc.x += wv*pv.x; acc.y += wv*pv.y; acc.z += wv*pv.z; acc.w += wv*pv.w;
            }
            u16x4 pk; pk.x=f2bf(acc.x); pk.y=f2bf(acc.y); pk.z=f2bf(acc.z); pk.w=f2bf(acc.w);
            *(u16x4*)&Mout[(z*32+ol)*128 + jq*4] = pk;
        }
        if (z == 0) {
            if (tid < 128) {
                float s = 0.f;
                for (int o = 0; o < 128; ++o) s += aH[o]*WH[o*320 + koff + tid];
                tS[tid] = s;
            }
            __syncthreads();
            if (tid < 128) {
                float s = 0.f;
                for (int i = 0; i < 128; ++i) s += tS[i]*projS[i*132 + tid];
                (part ? atgt : asrc)[h*128 + tid] = s;
            }
        }
    } else {
        __syncthreads();
        float local = 0.f;
        const int base = z*2048;
        for (int idx = base + tid; idx < base + 2048; idx += 256) {
            const int i = idx>>7, k = idx&127;
            if (i > k) continue;
            float s = 0.f;
            for (int q = 0; q < 32; ++q) {
                const float4 pi = *(const float4*)&projS[i*132 + q*4];
                const float4 pk = *(const float4*)&projS[k*132 + q*4];
                s += pi.x*pk.x + pi.y*pk.y + pi.z*pk.z + pi.w*pk.w;
            }
            if (i == k) { s -= 1.f; local += s*s; }
            else local += 2.f*s*s;
        }
        red[tid] = local;
        __syncthreads();
        for (int st = 128; st > 0; st >>= 1) {
            if (tid < st) red[tid] += red[tid+st];
            __syncthreads();
        }
        if (tid == 0) atomicAdd(&orth_part[h], red[0]);
        if (z == 0) {
            if (tid < 64) {
                float s = 0.f;
                for (int o = 0; o < 128; ++o) s += aH[o]*WH[o*320 + 256 + tid];
                arel[h*64 + tid] = s;
            }
            for (int idx = tid; idx < 8192; idx += 256) {
                const int r = idx & 63, o = idx >> 6;
                WcatT_bf[(size_t)o*256 + h*64 + r] = f2bf(WH[o*320 + 256 + r]);
            }
            if (h == 0 && tid == 0) {
                const float m = fmaxf(fmaxf(hw[0],hw[1]), fmaxf(hw[2],hw[3]));
                const float e0=expf(hw[0]-m), e1=expf(hw[1]-m), e2=expf(hw[2]-m), e3=expf(hw[3]-m);
                const float s = e0+e1+e2+e3;
                wsoft[0]=e0/s; wsoft[1]=e1/s; wsoft[2]=e2/s; wsoft[3]=e3/s;
            }
        }
    }
}

// fused: input -> bf16 + per-node score partials + degree histogram (edge domain)
__global__ __launch_bounds__(256) void k0_nodes(
    const float* __restrict__ input, const float* __restrict__ asrc, const float* __restrict__ atgt,
    const int* __restrict__ edge, const int* __restrict__ nhop,
    u16* __restrict__ in_bf, float* __restrict__ s_src, float* __restrict__ s_tgt,
    int* __restrict__ deg, int N, int E1, int E2)
{
    __shared__ float aS[512], tS[512];
    const int tid = threadIdx.x;
    for (int idx = tid; idx < 512; idx += 256) { aS[idx] = asrc[idx]; tS[idx] = atgt[idx]; }
    const int t = blockIdx.x*256 + tid;
    if (t < E1 + E2) {
        const int src = (t < E1) ? edge[t] : nhop[t-E1];
        atomicAdd(&deg[src], 1);
    }
    __syncthreads();
    const int n = t;
    if (n >= N) return;
    const float4* inr = (const float4*)(input + (size_t)n*128);
    u16* ob = in_bf + (size_t)n*128;
    float ss[4] = {0.f,0.f,0.f,0.f}, st[4] = {0.f,0.f,0.f,0.f};
    for (int q = 0; q < 32; ++q) {
        const float4 v = inr[q];
        u16x4 pk; pk.x=f2bf(v.x); pk.y=f2bf(v.y); pk.z=f2bf(v.z); pk.w=f2bf(v.w);
        *(u16x4*)(ob + q*4) = pk;
        #pragma unroll
        for (int hh = 0; hh < 4; ++hh) {
            const float4 av = *(const float4*)&aS[hh*128 + q*4];
            const float4 tv = *(const float4*)&tS[hh*128 + q*4];
            ss[hh] += v.x*av.x + v.y*av.y + v.z*av.z + v.w*av.w;
            st[hh] += v.x*tv.x + v.y*tv.y + v.z*tv.z + v.w*tv.w;
        }
    }
    float4 o1; o1.x=ss[0]; o1.y=ss[1]; o1.z=ss[2]; o1.w=ss[3];
    float4 o2; o2.x=st[0]; o2.y=st[1]; o2.z=st[2]; o2.w=st[3];
    *(float4*)(s_src + (size_t)n*4) = o1;
    *(float4*)(s_tgt + (size_t)n*4) = o2;
}

// Swapped-operand MFMA GEMM, all 8 matrices: mats 0-3 -> hsrc_tbl, 4-7 -> tbl.
__global__ __launch_bounds__(256) void k2_mfma(
    const u16* __restrict__ in_bf, const u16* __restrict__ M_bf,
    u16* __restrict__ hsrc_tbl, u16* __restrict__ tbl, int N)
{
    __shared__ u16 MS[16384];
    __shared__ u16 DW[4][16*136];
    const int tid = threadIdx.x;
    const int w = tid >> 6, lane = tid & 63;
    const int bid = blockIdx.x;
    const int chunk = gridDim.x >> 3;
    const int swz = (bid & 7)*chunk + (bid >> 3);
    const int n0 = (swz >> 3)*256;
    const int mat = swz & 7;
    const int m = lane & 15, kg = lane >> 4;

    {
        const u16* Mp = M_bf + (size_t)mat*16384;
        for (int c = tid; c < 2048; c += 256) {
            const int row = c >> 4, c16 = c & 15;
            const u16x8 v = *(const u16x8*)(Mp + row*128 + c16*8);
            *(u16x8*)((char*)MS + row*256 + ((c16*16) ^ ((row&7)<<4))) = v;
        }
    }
    __syncthreads();

    bf16x8 fa[8][4];
    #pragma unroll
    for (int nt = 0; nt < 8; ++nt) {
        const int row = nt*16 + m;
        #pragma unroll
        for (int ks = 0; ks < 4; ++ks) {
            const int c16 = ks*4 + kg;
            fa[nt][ks] = *(const bf16x8*)((const char*)MS + row*256 + ((c16*16) ^ ((row&7)<<4)));
        }
    }

    u16* outT = (mat < 4) ? (hsrc_tbl + mat*128) : (tbl + (mat-4)*128);

    for (int sub = 0; sub < 4; ++sub) {
        const int nrow = n0 + w*64 + sub*16 + m;
        const int nclamp = (nrow < N) ? nrow : (N-1);
        bf16x8 fb[4];
        #pragma unroll
        for (int ks = 0; ks < 4; ++ks)
            fb[ks] = *(const bf16x8*)(in_bf + (size_t)nclamp*128 + ks*32 + kg*8);
        f32x4 acc[8];
        #pragma unroll
        for (int nt = 0; nt < 8; ++nt) { acc[nt][0]=0.f; acc[nt][1]=0.f; acc[nt][2]=0.f; acc[nt][3]=0.f; }
        #pragma unroll
        for (int nt = 0; nt < 8; ++nt)
            #pragma unroll
            for (int ks = 0; ks < 4; ++ks)
                acc[nt] = __builtin_amdgcn_mfma_f32_16x16x32_bf16(fa[nt][ks], fb[ks], acc[nt], 0, 0, 0);
        #pragma unroll
        for (int nt = 0; nt < 8; ++nt) {
            unsigned lo, hi;
            asm("v_cvt_pk_bf16_f32 %0, %1, %2" : "=v"(lo) : "v"(acc[nt][0]), "v"(acc[nt][1]));
            asm("v_cvt_pk_bf16_f32 %0, %1, %2" : "=v"(hi) : "v"(acc[nt][2]), "v"(acc[nt][3]));
            uint2 pk; pk.x = lo; pk.y = hi;
            *(uint2*)&DW[w][m*136 + nt*16 + kg*4] = pk;
        }
        const int nb = n0 + w*64 + sub*16;
        #pragma unroll
        for (int k = 0; k < 4; ++k) {
            const int idx = lane + k*64;
            const int row = idx >> 4, seg = idx & 15;
            const int n = nb + row;
            if (n < N) {
                const bf16x8 v = *(const bf16x8*)&DW[w][row*136 + seg*8];
                *(bf16x8*)(outT + (size_t)n*512 + seg*8) = v;
            }
        }
    }
}

// scanA with scanB folded in via last-block-done lookback (nb <= 64).
__global__ __launch_bounds__(1024) void k_scanA(const int* __restrict__ deg, int* __restrict__ offsets,
                                                int* __restrict__ bsum, int* __restrict__ boff,
                                                int* __restrict__ sdone, int N, int nb)
{
    __shared__ int wsumS[16];
    __shared__ int ticketS;
    const int tid = threadIdx.x;
    const int lane = tid & 63, wid = tid >> 6;
    const int i0 = blockIdx.x*4096 + tid*4;
    int a0=0,a1=0,a2=0,a3=0;
    if (i0 + 3 < N) { const int4 t = *(const int4*)(deg + i0); a0=t.x; a1=t.y; a2=t.z; a3=t.w; }
    else { if (i0 < N) a0=deg[i0]; if (i0+1 < N) a1=deg[i0+1]; if (i0+2 < N) a2=deg[i0+2]; }
    const int s1=a0+a1, s2=s1+a2, s3=s2+a3;
    int s = s3;
    #pragma unroll
    for (int d = 1; d < 64; d <<= 1) { const int t = __shfl_up(s, d); if (lane >= d) s += t; }
    if (lane == 63) wsumS[wid] = s;
    __syncthreads();
    if (tid < 16) {
        int t = wsumS[tid];
        #pragma unroll
        for (int d = 1; d < 16; d <<= 1) { const int u = __shfl_up(t, d); if (tid >= d) t += u; }
        wsumS[tid] = t;
    }
    __syncthreads();
    const int ex = (wid ? wsumS[wid-1] : 0) + s - s3;
    if (i0 < N)     offsets[i0]   = ex;
    if (i0+1 < N)   offsets[i0+1] = ex + a0;
    if (i0+2 < N)   offsets[i0+2] = ex + s1;
    if (i0+3 < N)   offsets[i0+3] = ex + s2;
    if (tid == 0) {
        bsum[blockIdx.x] = wsumS[15];
        __threadfence();
        ticketS = atomicAdd(sdone, 1);
    }
    __syncthreads();
    if (ticketS == nb - 1 && tid < 64) {
        const int v = (tid < nb) ? atomicAdd(&bsum[tid], 0) : 0;
        int sv = v;
        #pragma unroll
        for (int d = 1; d < 64; d <<= 1) { const int t = __shfl_up(sv, d); if (tid >= d) sv += t; }
        if (tid < nb) boff[tid] = sv - v;
        if (tid == 63) offsets[N] = sv;
    }
}

// 3-phase fused edge pass.
__global__ __launch_bounds__(256) void k_fill2(
    const int* __restrict__ edge, const int* __restrict__ nhop,
    const float* __restrict__ emb1, const float* __restrict__ emb2,
    const float* __restrict__ s_src, const float* __restrict__ s_tgt,
    const float* __restrict__ arel,
    const int* __restrict__ offsets, const int* __restrict__ boff, int* __restrict__ cursor,
    int* __restrict__ csr_tgt, float* __restrict__ ee_perm, u16* __restrict__ emb_perm,
    int E1, int E2)
{
    __shared__ u16 embS[256*64];
    __shared__ float scS[256][4];
    __shared__ int pS[256];
    const int tid = threadIdx.x;
    const int g = tid >> 4, l = tid & 15;
    const int E = E1 + E2;
    const int ebase = blockIdx.x*256;

    {
        const float4 ar0 = *(const float4*)(arel + 0*64 + l*4);
        const float4 ar1 = *(const float4*)(arel + 1*64 + l*4);
        const float4 ar2 = *(const float4*)(arel + 2*64 + l*4);
        const float4 ar3 = *(const float4*)(arel + 3*64 + l*4);
        #pragma unroll 4
        for (int it = 0; it < 16; ++it) {
            const int el = it*16 + g;
            const int e = ebase + el;
            if (e >= E) continue;
            const float4 v = (e < E1) ? *(const float4*)(emb1 + (size_t)e*64 + l*4)
                                      : *(const float4*)(emb2 + (size_t)(e-E1)*64 + l*4);
            u16x4 pk; pk.x=f2bf(v.x); pk.y=f2bf(v.y); pk.z=f2bf(v.z); pk.w=f2bf(v.w);
            *(u16x4*)&embS[el*64 + l*4] = pk;
            float p0 = v.x*ar0.x + v.y*ar0.y + v.z*ar0.z + v.w*ar0.w;
            float p1 = v.x*ar1.x + v.y*ar1.y + v.z*ar1.z + v.w*ar1.w;
            float p2 = v.x*ar2.x + v.y*ar2.y + v.z*ar2.z + v.w*ar2.w;
            float p3 = v.x*ar3.x + v.y*ar3.y + v.z*ar3.z + v.w*ar3.w;
            #pragma unroll
            for (int d = 1; d < 16; d <<= 1) {
                p0 += __shfl_xor(p0, d);
                p1 += __shfl_xor(p1, d);
                p2 += __shfl_xor(p2, d);
                p3 += __shfl_xor(p3, d);
            }
            if (l == 0) {
                float4 sc; sc.x=p0; sc.y=p1; sc.z=p2; sc.w=p3;
                *(float4*)&scS[el][0] = sc;
            }
        }
    }
    __syncthreads();

    {
        const int e = ebase + tid;
        if (e < E) {
            int src, tgt;
            if (e < E1) { src = edge[e]; tgt = edge[E1+e]; }
            else { const int e2 = e-E1; src = nhop[e2]; tgt = nhop[E2+e2]; }
            const float4 s4 = *(const float4*)(s_src + (size_t)src*4);
            const float4 t4 = *(const float4*)(s_tgt + (size_t)tgt*4);
            const float4 pr = *(const float4*)&scS[tid][0];
            float4 eo;
            { const float sc = s4.x+t4.x+pr.x; eo.x = expf(sc>0.f ? -sc : -0.2f*sc); }
            { const float sc = s4.y+t4.y+pr.y; eo.y = expf(sc>0.f ? -sc : -0.2f*sc); }
            { const float sc = s4.z+t4.z+pr.z; eo.z = expf(sc>0.f ? -sc : -0.2f*sc); }
            { const float sc = s4.w+t4.w+pr.w; eo.w = expf(sc>0.f ? -sc : -0.2f*sc); }
            const int pos = atomicAdd(&cursor[src], 1);
            const int p = offsets[src] + boff[src>>12] + pos;
            csr_tgt[p] = tgt;
            *(float4*)(ee_perm + (size_t)p*4) = eo;
            pS[tid] = p;
        }
    }
    __syncthreads();

    #pragma unroll 4
    for (int it = 0; it < 16; ++it) {
        const int el = it*16 + g;
        const int e = ebase + el;
        if (e >= E) continue;
        const int p = pS[el];
        const u16x4 pk = *(const u16x4*)&embS[el*64 + l*4];
        *(u16x4*)(emb_perm + (size_t)p*64 + l*4) = pk;
    }
}

// per-node wave gather: depth-4 guarded pipeline + LDS metadata broadcast,
// persistent grid-stride blocks (amortizes per-block fixed costs).
__global__ __launch_bounds__(256) void k4_gather(
    const float* __restrict__ ee_perm, const int* __restrict__ offsets, const int* __restrict__ boff,
    const int* __restrict__ csr_tgt,
    const u16* __restrict__ emb_perm, const u16* __restrict__ tbl,
    const float* __restrict__ wsoft,
    u16* __restrict__ pout_bf, u16* __restrict__ semb_bf, float* __restrict__ rowsum4,
    int N)
{
    __shared__ float eeS[4][64][4];
    __shared__ int   tgS[4][64];
    const int lane = threadIdx.x & 63;
    const int wv = threadIdx.x >> 6;
    const int hl = lane >> 4;
    const int hoff = hl*128 + (lane & 15)*8;
    const int stride = gridDim.x*4;
    const float4 ws4 = *(const float4*)wsoft;

    union HT { u16x8 v; unsigned u[4]; };

    for (int n = blockIdx.x*4 + wv; n < N; n += stride) {

    float acc[8];
    #pragma unroll
    for (int j = 0; j < 8; ++j) acc[j] = 0.f;
    float sm0=0.f, sm1=0.f, sm2=0.f, sm3=0.f;
    float rsl0=0.f, rsl1=0.f, rsl2=0.f, rsl3=0.f;

    const int start = offsets[n] + boff[n>>12];
    const int end = (n+1 == N) ? offsets[N] : (offsets[n+1] + boff[(n+1)>>12]);
    for (int cb = start; cb < end; cb += 64) {
        const int rem = end - cb;
        const int cnt = rem < 64 ? rem : 64;    // wave-uniform
        int tgtL = 0;
        float4 eeL; eeL.x=0.f; eeL.y=0.f; eeL.z=0.f; eeL.w=0.f;
        if (lane < cnt) {
            tgtL = csr_tgt[cb + lane];
            eeL  = *(const float4*)(ee_perm + (size_t)(cb + lane)*4);
        }
        rsl0 += eeL.x; rsl1 += eeL.y; rsl2 += eeL.z; rsl3 += eeL.w;
        *(float4*)&eeS[wv][lane][0] = eeL;
        tgS[wv][lane] = tgtL;
        const int cp = (cnt + 3) & ~3;

        HT zz; zz.u[0]=0u; zz.u[1]=0u; zz.u[2]=0u; zz.u[3]=0u;
        HT ht0=zz, ht1=zz, ht2=zz, ht3=zz;
        u16 em0=0, em1=0, em2=0, em3=0;
#define K4_FETCH(J, IDX) { const int tg_ = tgS[wv][IDX]; \
            ht##J.v = *(const u16x8*)(tbl + (size_t)tg_*512 + hoff); \
            em##J = emb_perm[(size_t)(cb + (IDX))*64 + lane]; }
        if (0 < cnt) K4_FETCH(0, 0)
        if (1 < cnt) K4_FETCH(1, 1)
        if (2 < cnt) K4_FETCH(2, 2)
        if (3 < cnt) K4_FETCH(3, 3)

#define K4_STAGE(J) { \
            const float4 ee4 = *(const float4*)&eeS[wv][i+J][0]; \
            const float eh = eeS[wv][i+J][hl]; \
            _Pragma("unroll") \
            for (int p = 0; p < 4; ++p) { \
                union{unsigned u; float f;} lo_, hi_; \
                lo_.u = ht##J.u[p] << 16; hi_.u = ht##J.u[p] & 0xffff0000u; \
                acc[2*p]   += eh*lo_.f; \
                acc[2*p+1] += eh*hi_.f; \
            } \
            const float ev = bf2f(em##J); \
            sm0 += ee4.x*ev; sm1 += ee4.y*ev; sm2 += ee4.z*ev; sm3 += ee4.w*ev; \
            { const int ii = i + 4 + J; if (ii < cnt) K4_FETCH(J, ii) } }

        for (int i = 0; i < cp; i += 4) {
            K4_STAGE(0)
            K4_STAGE(1)
            K4_STAGE(2)
            K4_STAGE(3)
        }
#undef K4_STAGE
#undef K4_FETCH
    }

    #pragma unroll
    for (int d = 1; d < 64; d <<= 1) {
        rsl0 += __shfl_xor(rsl0, d);
        rsl1 += __shfl_xor(rsl1, d);
        rsl2 += __shfl_xor(rsl2, d);
        rsl3 += __shfl_xor(rsl3, d);
    }
    if (lane == 0) {
        float4 r4; r4.x=rsl0; r4.y=rsl1; r4.z=rsl2; r4.w=rsl3;
        *(float4*)(rowsum4 + (size_t)n*4) = r4;
    }

    const float wh = (hl==0)?ws4.x:(hl==1)?ws4.y:(hl==2)?ws4.z:ws4.w;
    float p[8];
    #pragma unroll
    for (int j = 0; j < 8; ++j) {
        float pv = wh*acc[j];
        pv += __shfl_xor(pv, 16);
        pv += __shfl_xor(pv, 32);
        p[j] = pv;
    }
    if (hl == 0) {
        u16 pk[8];
        #pragma unroll
        for (int j = 0; j < 8; ++j) pk[j] = f2bf(p[j]);
        *(u16x8*)(pout_bf + (size_t)n*128 + (lane & 15)*8) = *(u16x8*)pk;
    }
    u16* so = semb_bf + (size_t)n*256;
    so[lane]       = f2bf(ws4.x*sm0);
    so[64 + lane]  = f2bf(ws4.y*sm1);
    so[128 + lane] = f2bf(ws4.z*sm2);
    so[192 + lane] = f2bf(ws4.w*sm3);

    }   // grid-stride
}

// k5: 2 WcatT staging phases + epilogue streaming hsrc_tbl (rh-weighted) + pout.
__global__ __launch_bounds__(256) void k5_gemm(
    const u16* __restrict__ semb_bf, const u16* __restrict__ wcatT_bf,
    const u16* __restrict__ hsrc_tbl, const u16* __restrict__ pout_bf,
    const float* __restrict__ rowsum4, const float* __restrict__ wsoft,
    const float* __restrict__ orth_part,
    float* __restrict__ out, int N)
{
    __shared__ __align__(16) char smemU[4*16*132*4];   // 33792B: MS (32KB) / DW alias
    u16* MS = (u16*)smemU;
    float* DWbase = (float*)smemU;
    const int tid = threadIdx.x;
    if (blockIdx.x == 0 && tid == 0)
        out[(size_t)N*128] = 0.01f*(sqrtf(orth_part[0])+sqrtf(orth_part[1])+sqrtf(orth_part[2])+sqrtf(orth_part[3]));
    const int w = tid >> 6, lane = tid & 63;
    const int m = lane & 15, kg = lane >> 4;
    const int n0 = blockIdx.x*128;
    const float4 ws4 = *(const float4*)wsoft;

    int rowS[2];
    #pragma unroll
    for (int sub = 0; sub < 2; ++sub) {
        int r = n0 + w*32 + sub*16 + m; if (r >= N) r = N-1;
        rowS[sub] = r;
    }

    f32x4 acc[2][8];
    #pragma unroll
    for (int sub = 0; sub < 2; ++sub)
        #pragma unroll
        for (int nt = 0; nt < 8; ++nt) { acc[sub][nt][0]=0.f; acc[sub][nt][1]=0.f; acc[sub][nt][2]=0.f; acc[sub][nt][3]=0.f; }

    #pragma unroll
    for (int half = 0; half < 2; ++half) {
        __syncthreads();
        for (int c = tid; c < 2048; c += 256) {
            const int r = c >> 4, c16 = c & 15;
            const u16x8 v = *(const u16x8*)(wcatT_bf + (size_t)r*256 + half*128 + c16*8);
            *(u16x8*)((char*)MS + r*256 + ((c16*16) ^ ((r&7)<<4))) = v;
        }
        __syncthreads();
        #pragma unroll
        for (int sub = 0; sub < 2; ++sub) {
            bf16x8 fa[4];
            const u16* ap = semb_bf + (size_t)rowS[sub]*256 + half*128 + kg*8;
            #pragma unroll
            for (int ks = 0; ks < 4; ++ks) fa[ks] = *(const bf16x8*)(ap + ks*32);
            #pragma unroll
            for (int nt = 0; nt < 8; ++nt) {
                const int o = nt*16 + m;
                #pragma unroll
                for (int ks = 0; ks < 4; ++ks) {
                    const int c16 = ks*4 + kg;
                    const bf16x8 fb = *(const bf16x8*)((const char*)MS + o*256 + ((c16*16) ^ ((o&7)<<4)));
                    acc[sub][nt] = __builtin_amdgcn_mfma_f32_16x16x32_bf16(fa[ks], fb, acc[sub][nt], 0, 0, 0);
                }
            }
        }
    }

    // barrier before overwriting MS region with DW epilogue data
    __syncthreads();
    float* DW = DWbase + w*16*132;
    #pragma unroll
    for (int sub = 0; sub < 2; ++sub) {
        #pragma unroll
        for (int nt = 0; nt < 8; ++nt) {
            #pragma unroll
            for (int r = 0; r < 4; ++r)
                DW[(kg*4+r)*132 + nt*16 + m] = acc[sub][nt][r];
        }
        const int nb = n0 + w*32 + sub*16;
        #pragma unroll
        for (int k = 0; k < 8; ++k) {
            const int idx = lane + k*64;
            const int row = idx >> 5, q = idx & 31;
            const int n = nb + row;
            if (n < N) {
                const float4 d = *(const float4*)&DW[row*132 + q*4];
                const u16x4 pb = *(const u16x4*)(pout_bf + (size_t)n*128 + q*4);
                const float4 rs = *(const float4*)(rowsum4 + (size_t)n*4);
                const float rh0 = ws4.x*rs.x, rh1 = ws4.y*rs.y, rh2 = ws4.z*rs.z, rh3 = ws4.w*rs.w;
                const u16* hp = hsrc_tbl + (size_t)n*512 + q*4;
                const u16x4 h0 = *(const u16x4*)(hp);
                const u16x4 h1 = *(const u16x4*)(hp + 128);
                const u16x4 h2 = *(const u16x4*)(hp + 256);
                const u16x4 h3 = *(const u16x4*)(hp + 384);
                const float rinv = 1.0f / fmaxf(rs.w, 1e-12f);
                float v0 = (bf2f(pb.x) + d.x + rh0*bf2f(h0.x) + rh1*bf2f(h1.x) + rh2*bf2f(h2.x) + rh3*bf2f(h3.x))*rinv;
                float v1 = (bf2f(pb.y) + d.y + rh0*bf2f(h0.y) + rh1*bf2f(h1.y) + rh2*bf2f(h2.y) + rh3*bf2f(h3.y))*rinv;
                float v2 = (bf2f(pb.z) + d.z + rh0*bf2f(h0.z) + rh1*bf2f(h1.z) + rh2*bf2f(h2.z) + rh3*bf2f(h3.z))*rinv;
                float v3 = (bf2f(pb.w) + d.w + rh0*bf2f(h0.w) + rh1*bf2f(h1.w) + rh2*bf2f(h2.w) + rh3*bf2f(h3.w))*rinv;
                v0 = (v0 > 0.f) ? v0 : expm1f(v0);
                v1 = (v1 > 0.f) ? v1 : expm1f(v1);
                v2 = (v2 > 0.f) ? v2 : expm1f(v2);
                v3 = (v3 > 0.f) ? v3 : expm1f(v3);
                float4 r4; r4.x=v0; r4.y=v1; r4.z=v2; r4.w=v3;
                *(float4*)(out + (size_t)n*128 + q*4) = r4;
            }
        }
    }
}

extern "C" void kernel_launch(void* const* d_in, const int* in_sizes, int n_in,
                              void* d_out, int out_size, void* d_ws, size_t ws_size,
                              hipStream_t stream)
{
    const float* input = (const float*)d_in[0];
    const int*   edge  = (const int*)d_in[1];
    const float* emb1  = (const float*)d_in[2];
    const int*   nhop  = (const int*)d_in[3];
    const float* emb2  = (const float*)d_in[4];
    const float* proj  = (const float*)d_in[5];
    const float* W     = (const float*)d_in[6];
    const float* a     = (const float*)d_in[7];
    const float* hw    = (const float*)d_in[8];
    float* out = (float*)d_out;

    const int N  = in_sizes[0] / 128;
    const int E1 = in_sizes[1] / 2;
    const int E2 = in_sizes[3] / 2;
    const int E  = E1 + E2;
    (void)n_in; (void)out_size; (void)ws_size;

    char* wsb = (char*)d_ws;
    size_t off = 0;
    auto alloc = [&](size_t bytes) -> char* {
        char* p = wsb + off;
        off += (bytes + 255) & ~(size_t)255;
        return p;
    };
    u16*   in_bf    = (u16*)alloc((size_t)N*128*2);
    u16*   tbl      = (u16*)alloc((size_t)N*512*2);
    u16*   hsrc_tbl = (u16*)alloc((size_t)N*512*2);
    u16*   semb_bf  = (u16*)alloc((size_t)N*256*2);
    u16*   pout_bf  = (u16*)alloc((size_t)N*128*2);
    u16*   emb_perm = (u16*)alloc((size_t)E*64*2);
    float* ee_perm  = (float*)alloc((size_t)E*4*4);
    int*   csr_tgt  = (int*)alloc((size_t)E*4);
    u16*   M_bf     = (u16*)alloc((size_t)8*16384*2);
    u16*   WcatT_bf = (u16*)alloc((size_t)128*256*2);
    float* asrc     = (float*)alloc(512*4);
    float* atgt     = (float*)alloc(512*4);
    float* arel     = (float*)alloc(256*4);
    float* s_src    = (float*)alloc((size_t)N*4*4);
    float* s_tgt    = (float*)alloc((size_t)N*4*4);
    float* wsoft    = (float*)alloc(4*4);
    float* rowsum4  = (float*)alloc((size_t)N*4*4);
    int*   offsets  = (int*)alloc((size_t)(N+1)*4);
    int*   bsum     = (int*)alloc(64*4);
    int*   boff     = (int*)alloc(64*4);
    const size_t zoff0 = off;
    float* orth_part= (float*)alloc(4*4);
    int*   deg      = (int*)alloc((size_t)N*4);
    int*   cursor   = (int*)alloc((size_t)N*4);
    int*   sdone    = (int*)alloc(4);
    const size_t zoff1 = off;

    hipMemsetAsync(wsb + zoff0, 0, zoff1 - zoff0, stream);

    const int nbScan = (N + 4095) / 4096;
    const int nx = (N + 255) / 256;
    const int nx2 = (N + 127) / 128;
    const int nk0 = ((E > N ? E : N) + 255) / 256;
    int nb4 = (N + 3) / 4; if (nb4 > 3072) nb4 = 3072;

    k1_prep<<<dim3(NHEAD,3,8), dim3(256), 0, stream>>>(proj, W, a, hw, M_bf,
                                                       asrc, atgt, arel, WcatT_bf, wsoft, orth_part);
    k0_nodes<<<dim3(nk0), dim3(256), 0, stream>>>(input, asrc, atgt, edge, nhop,
                                                  in_bf, s_src, s_tgt, deg, N, E1, E2);
    k2_mfma<<<dim3(nx*8), dim3(256), 0, stream>>>(in_bf, M_bf, hsrc_tbl, tbl, N);
    k_scanA<<<dim3(nbScan), dim3(1024), 0, stream>>>(deg, offsets, bsum, boff, sdone, N, nbScan);
    k_fill2<<<dim3((E+255)/256), dim3(256), 0, stream>>>(edge, nhop, emb1, emb2, s_src, s_tgt,
                                                         arel, offsets, boff, cursor,
                                                         csr_tgt, ee_perm, emb_perm, E1, E2);
    k4_gather<<<dim3(nb4), dim3(256), 0, stream>>>(ee_perm, offsets, boff, csr_tgt, emb_perm,
                                                   tbl, wsoft, pout_bf, semb_bf, rowsum4, N);
    k5_gemm<<<dim3(nx2), dim3(256), 0, stream>>>(semb_bf, WcatT_bf, hsrc_tbl, pout_bf,
                                                 rowsum4, wsoft, orth_part, out, N);
}

// Round 20
// 220.223 us; speedup vs baseline: 1.1098x; 1.0118x over previous
//
#include <hip/hip_runtime.h>
#include <math.h>

// SpGraphAttentionLayer on MI355X — round 20 (revert to verified round-18 best).
// fp8 tgt-table failed numerics (6% mantissa error vs ~1.8% relative threshold);
// bf16 is the minimum width. This is the 222.8us configuration: persistent
// depth-4 k4 gather, hsrc/tgt table split (k5 streams hsrc), 3-phase fill,
// scan folded into one kernel via last-block lookback.

#define NHEAD 4

typedef unsigned short u16;
typedef __attribute__((ext_vector_type(4))) unsigned short u16x4;
typedef __attribute__((ext_vector_type(8))) unsigned short u16x8;
typedef __attribute__((ext_vector_type(8))) short bf16x8;
typedef __attribute__((ext_vector_type(4))) float f32x4;

__device__ __forceinline__ float bf2f(u16 v) {
    union { unsigned u; float f; } x; x.u = ((unsigned)v) << 16; return x.f;
}
__device__ __forceinline__ u16 f2bf(float f) {
    union { float f; unsigned u; } x; x.f = f;
    const unsigned r = x.u + 0x7FFFu + ((x.u >> 16) & 1u);
    return (u16)(r >> 16);
}

__global__ __launch_bounds__(256) void k1_prep(
    const float* __restrict__ proj, const float* __restrict__ W,
    const float* __restrict__ a, const float* __restrict__ hw,
    u16* __restrict__ M_bf,
    float* __restrict__ asrc, float* __restrict__ atgt, float* __restrict__ arel,
    u16* __restrict__ WcatT_bf, float* __restrict__ wsoft,
    float* __restrict__ orth_part)
{
    __shared__ float projS[128*132];
    __shared__ float WS[32*132];
    __shared__ float tS[128];
    __shared__ float red[256];
    const int h = blockIdx.x;
    const int part = blockIdx.y;
    const int z = blockIdx.z;
    const int tid = threadIdx.x;
    if (part < 2 && z >= 4) return;
    const float* projH = proj + h*(128*128);
    const float* WH = W + h*(128*320);
    const float* aH = a + h*128;

    {
        const float4* p4 = (const float4*)projH;
        for (int idx = tid; idx < 4096; idx += 256)
            *(float4*)&projS[(idx>>5)*132 + (idx&31)*4] = p4[idx];
    }

    if (part < 2) {
        const int koff = part ? 128 : 0;
        for (int idx = tid; idx < 1024; idx += 256) {
            const int ol = idx>>5, jq = idx&31;
            *(float4*)&WS[ol*132 + jq*4] = *(const float4*)&WH[(z*32+ol)*320 + koff + jq*4];
        }
        __syncthreads();
        u16* Mout = M_bf + ((size_t)(part*4 + h))*16384;
        for (int idx = tid; idx < 1024; idx += 256) {
            const int ol = idx>>5, jq = idx&31;
            float4 acc; acc.x=0.f; acc.y=0.f; acc.z=0.f; acc.w=0.f;
            for (int i = 0; i < 128; ++i) {
                const float wv = WS[ol*132 + i];
                const float4 pv = *(const float4*)&projS[i*132 + jq*4];
                acc.x += wv*pv.x; acc.y += wv*pv.y; acc.z += wv*pv.z; acc.w += wv*pv.w;
            }
            u16x4 pk; pk.x=f2bf(acc.x); pk.y=f2bf(acc.y); pk.z=f2bf(acc.z); pk.w=f2bf(acc.w);
            *(u16x4*)&Mout[(z*32+ol)*128 + jq*4] = pk;
        }
        if (z == 0) {
            if (tid < 128) {
                float s = 0.f;
                for (int o = 0; o < 128; ++o) s += aH[o]*WH[o*320 + koff + tid];
                tS[tid] = s;
            }
            __syncthreads();
            if (tid < 128) {
                float s = 0.f;
                for (int i = 0; i < 128; ++i) s += tS[i]*projS[i*132 + tid];
                (part ? atgt : asrc)[h*128 + tid] = s;
            }
        }
    } else {
        __syncthreads();
        float local = 0.f;
        const int base = z*2048;
        for (int idx = base + tid; idx < base + 2048; idx += 256) {
            const int i = idx>>7, k = idx&127;
            if (i > k) continue;
            float s = 0.f;
            for (int q = 0; q < 32; ++q) {
                const float4 pi = *(const float4*)&projS[i*132 + q*4];
                const float4 pk = *(const float4*)&projS[k*132 + q*4];
                s += pi.x*pk.x + pi.y*pk.y + pi.z*pk.z + pi.w*pk.w;
            }
            if (i == k) { s -= 1.f; local += s*s; }
            else local += 2.f*s*s;
        }
        red[tid] = local;
        __syncthreads();
        for (int st = 128; st > 0; st >>= 1) {
            if (tid < st) red[tid] += red[tid+st];
            __syncthreads();
        }
        if (tid == 0) atomicAdd(&orth_part[h], red[0]);
        if (z == 0) {
            if (tid < 64) {
                float s = 0.f;
                for (int o = 0; o < 128; ++o) s += aH[o]*WH[o*320 + 256 + tid];
                arel[h*64 + tid] = s;
            }
            for (int idx = tid; idx < 8192; idx += 256) {
                const int r = idx & 63, o = idx >> 6;
                WcatT_bf[(size_t)o*256 + h*64 + r] = f2bf(WH[o*320 + 256 + r]);
            }
            if (h == 0 && tid == 0) {
                const float m = fmaxf(fmaxf(hw[0],hw[1]), fmaxf(hw[2],hw[3]));
                const float e0=expf(hw[0]-m), e1=expf(hw[1]-m), e2=expf(hw[2]-m), e3=expf(hw[3]-m);
                const float s = e0+e1+e2+e3;
                wsoft[0]=e0/s; wsoft[1]=e1/s; wsoft[2]=e2/s; wsoft[3]=e3/s;
            }
        }
    }
}

// fused: input -> bf16 + per-node score partials + degree histogram (edge domain)
__global__ __launch_bounds__(256) void k0_nodes(
    const float* __restrict__ input, const float* __restrict__ asrc, const float* __restrict__ atgt,
    const int* __restrict__ edge, const int* __restrict__ nhop,
    u16* __restrict__ in_bf, float* __restrict__ s_src, float* __restrict__ s_tgt,
    int* __restrict__ deg, int N, int E1, int E2)
{
    __shared__ float aS[512], tS[512];
    const int tid = threadIdx.x;
    for (int idx = tid; idx < 512; idx += 256) { aS[idx] = asrc[idx]; tS[idx] = atgt[idx]; }
    const int t = blockIdx.x*256 + tid;
    if (t < E1 + E2) {
        const int src = (t < E1) ? edge[t] : nhop[t-E1];
        atomicAdd(&deg[src], 1);
    }
    __syncthreads();
    const int n = t;
    if (n >= N) return;
    const float4* inr = (const float4*)(input + (size_t)n*128);
    u16* ob = in_bf + (size_t)n*128;
    float ss[4] = {0.f,0.f,0.f,0.f}, st[4] = {0.f,0.f,0.f,0.f};
    for (int q = 0; q < 32; ++q) {
        const float4 v = inr[q];
        u16x4 pk; pk.x=f2bf(v.x); pk.y=f2bf(v.y); pk.z=f2bf(v.z); pk.w=f2bf(v.w);
        *(u16x4*)(ob + q*4) = pk;
        #pragma unroll
        for (int hh = 0; hh < 4; ++hh) {
            const float4 av = *(const float4*)&aS[hh*128 + q*4];
            const float4 tv = *(const float4*)&tS[hh*128 + q*4];
            ss[hh] += v.x*av.x + v.y*av.y + v.z*av.z + v.w*av.w;
            st[hh] += v.x*tv.x + v.y*tv.y + v.z*tv.z + v.w*tv.w;
        }
    }
    float4 o1; o1.x=ss[0]; o1.y=ss[1]; o1.z=ss[2]; o1.w=ss[3];
    float4 o2; o2.x=st[0]; o2.y=st[1]; o2.z=st[2]; o2.w=st[3];
    *(float4*)(s_src + (size_t)n*4) = o1;
    *(float4*)(s_tgt + (size_t)n*4) = o2;
}

// Swapped-operand MFMA GEMM, all 8 matrices: mats 0-3 -> hsrc_tbl, 4-7 -> tbl.
__global__ __launch_bounds__(256) void k2_mfma(
    const u16* __restrict__ in_bf, const u16* __restrict__ M_bf,
    u16* __restrict__ hsrc_tbl, u16* __restrict__ tbl, int N)
{
    __shared__ u16 MS[16384];
    __shared__ u16 DW[4][16*136];
    const int tid = threadIdx.x;
    const int w = tid >> 6, lane = tid & 63;
    const int bid = blockIdx.x;
    const int chunk = gridDim.x >> 3;
    const int swz = (bid & 7)*chunk + (bid >> 3);
    const int n0 = (swz >> 3)*256;
    const int mat = swz & 7;
    const int m = lane & 15, kg = lane >> 4;

    {
        const u16* Mp = M_bf + (size_t)mat*16384;
        for (int c = tid; c < 2048; c += 256) {
            const int row = c >> 4, c16 = c & 15;
            const u16x8 v = *(const u16x8*)(Mp + row*128 + c16*8);
            *(u16x8*)((char*)MS + row*256 + ((c16*16) ^ ((row&7)<<4))) = v;
        }
    }
    __syncthreads();

    bf16x8 fa[8][4];
    #pragma unroll
    for (int nt = 0; nt < 8; ++nt) {
        const int row = nt*16 + m;
        #pragma unroll
        for (int ks = 0; ks < 4; ++ks) {
            const int c16 = ks*4 + kg;
            fa[nt][ks] = *(const bf16x8*)((const char*)MS + row*256 + ((c16*16) ^ ((row&7)<<4)));
        }
    }

    u16* outT = (mat < 4) ? (hsrc_tbl + mat*128) : (tbl + (mat-4)*128);

    for (int sub = 0; sub < 4; ++sub) {
        const int nrow = n0 + w*64 + sub*16 + m;
        const int nclamp = (nrow < N) ? nrow : (N-1);
        bf16x8 fb[4];
        #pragma unroll
        for (int ks = 0; ks < 4; ++ks)
            fb[ks] = *(const bf16x8*)(in_bf + (size_t)nclamp*128 + ks*32 + kg*8);
        f32x4 acc[8];
        #pragma unroll
        for (int nt = 0; nt < 8; ++nt) { acc[nt][0]=0.f; acc[nt][1]=0.f; acc[nt][2]=0.f; acc[nt][3]=0.f; }
        #pragma unroll
        for (int nt = 0; nt < 8; ++nt)
            #pragma unroll
            for (int ks = 0; ks < 4; ++ks)
                acc[nt] = __builtin_amdgcn_mfma_f32_16x16x32_bf16(fa[nt][ks], fb[ks], acc[nt], 0, 0, 0);
        #pragma unroll
        for (int nt = 0; nt < 8; ++nt) {
            unsigned lo, hi;
            asm("v_cvt_pk_bf16_f32 %0, %1, %2" : "=v"(lo) : "v"(acc[nt][0]), "v"(acc[nt][1]));
            asm("v_cvt_pk_bf16_f32 %0, %1, %2" : "=v"(hi) : "v"(acc[nt][2]), "v"(acc[nt][3]));
            uint2 pk; pk.x = lo; pk.y = hi;
            *(uint2*)&DW[w][m*136 + nt*16 + kg*4] = pk;
        }
        const int nb = n0 + w*64 + sub*16;
        #pragma unroll
        for (int k = 0; k < 4; ++k) {
            const int idx = lane + k*64;
            const int row = idx >> 4, seg = idx & 15;
            const int n = nb + row;
            if (n < N) {
                const bf16x8 v = *(const bf16x8*)&DW[w][row*136 + seg*8];
                *(bf16x8*)(outT + (size_t)n*512 + seg*8) = v;
            }
        }
    }
}

// scanA with scanB folded in via last-block-done lookback (nb <= 64).
__global__ __launch_bounds__(1024) void k_scanA(const int* __restrict__ deg, int* __restrict__ offsets,
                                                int* __restrict__ bsum, int* __restrict__ boff,
                                                int* __restrict__ sdone, int N, int nb)
{
    __shared__ int wsumS[16];
    __shared__ int ticketS;
    const int tid = threadIdx.x;
    const int lane = tid & 63, wid = tid >> 6;
    const int i0 = blockIdx.x*4096 + tid*4;
    int a0=0,a1=0,a2=0,a3=0;
    if (i0 + 3 < N) { const int4 t = *(const int4*)(deg + i0); a0=t.x; a1=t.y; a2=t.z; a3=t.w; }
    else { if (i0 < N) a0=deg[i0]; if (i0+1 < N) a1=deg[i0+1]; if (i0+2 < N) a2=deg[i0+2]; }
    const int s1=a0+a1, s2=s1+a2, s3=s2+a3;
    int s = s3;
    #pragma unroll
    for (int d = 1; d < 64; d <<= 1) { const int t = __shfl_up(s, d); if (lane >= d) s += t; }
    if (lane == 63) wsumS[wid] = s;
    __syncthreads();
    if (tid < 16) {
        int t = wsumS[tid];
        #pragma unroll
        for (int d = 1; d < 16; d <<= 1) { const int u = __shfl_up(t, d); if (tid >= d) t += u; }
        wsumS[tid] = t;
    }
    __syncthreads();
    const int ex = (wid ? wsumS[wid-1] : 0) + s - s3;
    if (i0 < N)     offsets[i0]   = ex;
    if (i0+1 < N)   offsets[i0+1] = ex + a0;
    if (i0+2 < N)   offsets[i0+2] = ex + s1;
    if (i0+3 < N)   offsets[i0+3] = ex + s2;
    if (tid == 0) {
        bsum[blockIdx.x] = wsumS[15];
        __threadfence();
        ticketS = atomicAdd(sdone, 1);
    }
    __syncthreads();
    if (ticketS == nb - 1 && tid < 64) {
        const int v = (tid < nb) ? atomicAdd(&bsum[tid], 0) : 0;
        int sv = v;
        #pragma unroll
        for (int d = 1; d < 64; d <<= 1) { const int t = __shfl_up(sv, d); if (tid >= d) sv += t; }
        if (tid < nb) boff[tid] = sv - v;
        if (tid == 63) offsets[N] = sv;
    }
}

// 3-phase fused edge pass.
__global__ __launch_bounds__(256) void k_fill2(
    const int* __restrict__ edge, const int* __restrict__ nhop,
    const float* __restrict__ emb1, const float* __restrict__ emb2,
    const float* __restrict__ s_src, const float* __restrict__ s_tgt,
    const float* __restrict__ arel,
    const int* __restrict__ offsets, const int* __restrict__ boff, int* __restrict__ cursor,
    int* __restrict__ csr_tgt, float* __restrict__ ee_perm, u16* __restrict__ emb_perm,
    int E1, int E2)
{
    __shared__ u16 embS[256*64];
    __shared__ float scS[256][4];
    __shared__ int pS[256];
    const int tid = threadIdx.x;
    const int g = tid >> 4, l = tid & 15;
    const int E = E1 + E2;
    const int ebase = blockIdx.x*256;

    {
        const float4 ar0 = *(const float4*)(arel + 0*64 + l*4);
        const float4 ar1 = *(const float4*)(arel + 1*64 + l*4);
        const float4 ar2 = *(const float4*)(arel + 2*64 + l*4);
        const float4 ar3 = *(const float4*)(arel + 3*64 + l*4);
        #pragma unroll 4
        for (int it = 0; it < 16; ++it) {
            const int el = it*16 + g;
            const int e = ebase + el;
            if (e >= E) continue;
            const float4 v = (e < E1) ? *(const float4*)(emb1 + (size_t)e*64 + l*4)
                                      : *(const float4*)(emb2 + (size_t)(e-E1)*64 + l*4);
            u16x4 pk; pk.x=f2bf(v.x); pk.y=f2bf(v.y); pk.z=f2bf(v.z); pk.w=f2bf(v.w);
            *(u16x4*)&embS[el*64 + l*4] = pk;
            float p0 = v.x*ar0.x + v.y*ar0.y + v.z*ar0.z + v.w*ar0.w;
            float p1 = v.x*ar1.x + v.y*ar1.y + v.z*ar1.z + v.w*ar1.w;
            float p2 = v.x*ar2.x + v.y*ar2.y + v.z*ar2.z + v.w*ar2.w;
            float p3 = v.x*ar3.x + v.y*ar3.y + v.z*ar3.z + v.w*ar3.w;
            #pragma unroll
            for (int d = 1; d < 16; d <<= 1) {
                p0 += __shfl_xor(p0, d);
                p1 += __shfl_xor(p1, d);
                p2 += __shfl_xor(p2, d);
                p3 += __shfl_xor(p3, d);
            }
            if (l == 0) {
                float4 sc; sc.x=p0; sc.y=p1; sc.z=p2; sc.w=p3;
                *(float4*)&scS[el][0] = sc;
            }
        }
    }
    __syncthreads();

    {
        const int e = ebase + tid;
        if (e < E) {
            int src, tgt;
            if (e < E1) { src = edge[e]; tgt = edge[E1+e]; }
            else { const int e2 = e-E1; src = nhop[e2]; tgt = nhop[E2+e2]; }
            const float4 s4 = *(const float4*)(s_src + (size_t)src*4);
            const float4 t4 = *(const float4*)(s_tgt + (size_t)tgt*4);
            const float4 pr = *(const float4*)&scS[tid][0];
            float4 eo;
            { const float sc = s4.x+t4.x+pr.x; eo.x = expf(sc>0.f ? -sc : -0.2f*sc); }
            { const float sc = s4.y+t4.y+pr.y; eo.y = expf(sc>0.f ? -sc : -0.2f*sc); }
            { const float sc = s4.z+t4.z+pr.z; eo.z = expf(sc>0.f ? -sc : -0.2f*sc); }
            { const float sc = s4.w+t4.w+pr.w; eo.w = expf(sc>0.f ? -sc : -0.2f*sc); }
            const int pos = atomicAdd(&cursor[src], 1);
            const int p = offsets[src] + boff[src>>12] + pos;
            csr_tgt[p] = tgt;
            *(float4*)(ee_perm + (size_t)p*4) = eo;
            pS[tid] = p;
        }
    }
    __syncthreads();

    #pragma unroll 4
    for (int it = 0; it < 16; ++it) {
        const int el = it*16 + g;
        const int e = ebase + el;
        if (e >= E) continue;
        const int p = pS[el];
        const u16x4 pk = *(const u16x4*)&embS[el*64 + l*4];
        *(u16x4*)(emb_perm + (size_t)p*64 + l*4) = pk;
    }
}

// per-node wave gather: depth-4 guarded pipeline + LDS metadata broadcast,
// persistent grid-stride blocks.
__global__ __launch_bounds__(256) void k4_gather(
    const float* __restrict__ ee_perm, const int* __restrict__ offsets, const int* __restrict__ boff,
    const int* __restrict__ csr_tgt,
    const u16* __restrict__ emb_perm, const u16* __restrict__ tbl,
    const float* __restrict__ wsoft,
    u16* __restrict__ pout_bf, u16* __restrict__ semb_bf, float* __restrict__ rowsum4,
    int N)
{
    __shared__ float eeS[4][64][4];
    __shared__ int   tgS[4][64];
    const int lane = threadIdx.x & 63;
    const int wv = threadIdx.x >> 6;
    const int hl = lane >> 4;
    const int hoff = hl*128 + (lane & 15)*8;
    const int stride = gridDim.x*4;
    const float4 ws4 = *(const float4*)wsoft;

    union HT { u16x8 v; unsigned u[4]; };

    for (int n = blockIdx.x*4 + wv; n < N; n += stride) {

    float acc[8];
    #pragma unroll
    for (int j = 0; j < 8; ++j) acc[j] = 0.f;
    float sm0=0.f, sm1=0.f, sm2=0.f, sm3=0.f;
    float rsl0=0.f, rsl1=0.f, rsl2=0.f, rsl3=0.f;

    const int start = offsets[n] + boff[n>>12];
    const int end = (n+1 == N) ? offsets[N] : (offsets[n+1] + boff[(n+1)>>12]);
    for (int cb = start; cb < end; cb += 64) {
        const int rem = end - cb;
        const int cnt = rem < 64 ? rem : 64;    // wave-uniform
        int tgtL = 0;
        float4 eeL; eeL.x=0.f; eeL.y=0.f; eeL.z=0.f; eeL.w=0.f;
        if (lane < cnt) {
            tgtL = csr_tgt[cb + lane];
            eeL  = *(const float4*)(ee_perm + (size_t)(cb + lane)*4);
        }
        rsl0 += eeL.x; rsl1 += eeL.y; rsl2 += eeL.z; rsl3 += eeL.w;
        *(float4*)&eeS[wv][lane][0] = eeL;
        tgS[wv][lane] = tgtL;
        const int cp = (cnt + 3) & ~3;

        HT zz; zz.u[0]=0u; zz.u[1]=0u; zz.u[2]=0u; zz.u[3]=0u;
        HT ht0=zz, ht1=zz, ht2=zz, ht3=zz;
        u16 em0=0, em1=0, em2=0, em3=0;
#define K4_FETCH(J, IDX) { const int tg_ = tgS[wv][IDX]; \
            ht##J.v = *(const u16x8*)(tbl + (size_t)tg_*512 + hoff); \
            em##J = emb_perm[(size_t)(cb + (IDX))*64 + lane]; }
        if (0 < cnt) K4_FETCH(0, 0)
        if (1 < cnt) K4_FETCH(1, 1)
        if (2 < cnt) K4_FETCH(2, 2)
        if (3 < cnt) K4_FETCH(3, 3)

#define K4_STAGE(J) { \
            const float4 ee4 = *(const float4*)&eeS[wv][i+J][0]; \
            const float eh = eeS[wv][i+J][hl]; \
            _Pragma("unroll") \
            for (int p = 0; p < 4; ++p) { \
                union{unsigned u; float f;} lo_, hi_; \
                lo_.u = ht##J.u[p] << 16; hi_.u = ht##J.u[p] & 0xffff0000u; \
                acc[2*p]   += eh*lo_.f; \
                acc[2*p+1] += eh*hi_.f; \
            } \
            const float ev = bf2f(em##J); \
            sm0 += ee4.x*ev; sm1 += ee4.y*ev; sm2 += ee4.z*ev; sm3 += ee4.w*ev; \
            { const int ii = i + 4 + J; if (ii < cnt) K4_FETCH(J, ii) } }

        for (int i = 0; i < cp; i += 4) {
            K4_STAGE(0)
            K4_STAGE(1)
            K4_STAGE(2)
            K4_STAGE(3)
        }
#undef K4_STAGE
#undef K4_FETCH
    }

    #pragma unroll
    for (int d = 1; d < 64; d <<= 1) {
        rsl0 += __shfl_xor(rsl0, d);
        rsl1 += __shfl_xor(rsl1, d);
        rsl2 += __shfl_xor(rsl2, d);
        rsl3 += __shfl_xor(rsl3, d);
    }
    if (lane == 0) {
        float4 r4; r4.x=rsl0; r4.y=rsl1; r4.z=rsl2; r4.w=rsl3;
        *(float4*)(rowsum4 + (size_t)n*4) = r4;
    }

    const float wh = (hl==0)?ws4.x:(hl==1)?ws4.y:(hl==2)?ws4.z:ws4.w;
    float p[8];
    #pragma unroll
    for (int j = 0; j < 8; ++j) {
        float pv = wh*acc[j];
        pv += __shfl_xor(pv, 16);
        pv += __shfl_xor(pv, 32);
        p[j] = pv;
    }
    if (hl == 0) {
        u16 pk[8];
        #pragma unroll
        for (int j = 0; j < 8; ++j) pk[j] = f2bf(p[j]);
        *(u16x8*)(pout_bf + (size_t)n*128 + (lane & 15)*8) = *(u16x8*)pk;
    }
    u16* so = semb_bf + (size_t)n*256;
    so[lane]       = f2bf(ws4.x*sm0);
    so[64 + lane]  = f2bf(ws4.y*sm1);
    so[128 + lane] = f2bf(ws4.z*sm2);
    so[192 + lane] = f2bf(ws4.w*sm3);

    }   // grid-stride
}

// k5: 2 WcatT staging phases + epilogue streaming hsrc_tbl (rh-weighted) + pout.
__global__ __launch_bounds__(256) void k5_gemm(
    const u16* __restrict__ semb_bf, const u16* __restrict__ wcatT_bf,
    const u16* __restrict__ hsrc_tbl, const u16* __restrict__ pout_bf,
    const float* __restrict__ rowsum4, const float* __restrict__ wsoft,
    const float* __restrict__ orth_part,
    float* __restrict__ out, int N)
{
    __shared__ __align__(16) char smemU[4*16*132*4];   // 33792B: MS (32KB) / DW alias
    u16* MS = (u16*)smemU;
    float* DWbase = (float*)smemU;
    const int tid = threadIdx.x;
    if (blockIdx.x == 0 && tid == 0)
        out[(size_t)N*128] = 0.01f*(sqrtf(orth_part[0])+sqrtf(orth_part[1])+sqrtf(orth_part[2])+sqrtf(orth_part[3]));
    const int w = tid >> 6, lane = tid & 63;
    const int m = lane & 15, kg = lane >> 4;
    const int n0 = blockIdx.x*128;
    const float4 ws4 = *(const float4*)wsoft;

    int rowS[2];
    #pragma unroll
    for (int sub = 0; sub < 2; ++sub) {
        int r = n0 + w*32 + sub*16 + m; if (r >= N) r = N-1;
        rowS[sub] = r;
    }

    f32x4 acc[2][8];
    #pragma unroll
    for (int sub = 0; sub < 2; ++sub)
        #pragma unroll
        for (int nt = 0; nt < 8; ++nt) { acc[sub][nt][0]=0.f; acc[sub][nt][1]=0.f; acc[sub][nt][2]=0.f; acc[sub][nt][3]=0.f; }

    #pragma unroll
    for (int half = 0; half < 2; ++half) {
        __syncthreads();
        for (int c = tid; c < 2048; c += 256) {
            const int r = c >> 4, c16 = c & 15;
            const u16x8 v = *(const u16x8*)(wcatT_bf + (size_t)r*256 + half*128 + c16*8);
            *(u16x8*)((char*)MS + r*256 + ((c16*16) ^ ((r&7)<<4))) = v;
        }
        __syncthreads();
        #pragma unroll
        for (int sub = 0; sub < 2; ++sub) {
            bf16x8 fa[4];
            const u16* ap = semb_bf + (size_t)rowS[sub]*256 + half*128 + kg*8;
            #pragma unroll
            for (int ks = 0; ks < 4; ++ks) fa[ks] = *(const bf16x8*)(ap + ks*32);
            #pragma unroll
            for (int nt = 0; nt < 8; ++nt) {
                const int o = nt*16 + m;
                #pragma unroll
                for (int ks = 0; ks < 4; ++ks) {
                    const int c16 = ks*4 + kg;
                    const bf16x8 fb = *(const bf16x8*)((const char*)MS + o*256 + ((c16*16) ^ ((o&7)<<4)));
                    acc[sub][nt] = __builtin_amdgcn_mfma_f32_16x16x32_bf16(fa[ks], fb, acc[sub][nt], 0, 0, 0);
                }
            }
        }
    }

    // barrier before overwriting MS region with DW epilogue data
    __syncthreads();
    float* DW = DWbase + w*16*132;
    #pragma unroll
    for (int sub = 0; sub < 2; ++sub) {
        #pragma unroll
        for (int nt = 0; nt < 8; ++nt) {
            #pragma unroll
            for (int r = 0; r < 4; ++r)
                DW[(kg*4+r)*132 + nt*16 + m] = acc[sub][nt][r];
        }
        const int nb = n0 + w*32 + sub*16;
        #pragma unroll
        for (int k = 0; k < 8; ++k) {
            const int idx = lane + k*64;
            const int row = idx >> 5, q = idx & 31;
            const int n = nb + row;
            if (n < N) {
                const float4 d = *(const float4*)&DW[row*132 + q*4];
                const u16x4 pb = *(const u16x4*)(pout_bf + (size_t)n*128 + q*4);
                const float4 rs = *(const float4*)(rowsum4 + (size_t)n*4);
                const float rh0 = ws4.x*rs.x, rh1 = ws4.y*rs.y, rh2 = ws4.z*rs.z, rh3 = ws4.w*rs.w;
                const u16* hp = hsrc_tbl + (size_t)n*512 + q*4;
                const u16x4 h0 = *(const u16x4*)(hp);
                const u16x4 h1 = *(const u16x4*)(hp + 128);
                const u16x4 h2 = *(const u16x4*)(hp + 256);
                const u16x4 h3 = *(const u16x4*)(hp + 384);
                const float rinv = 1.0f / fmaxf(rs.w, 1e-12f);
                float v0 = (bf2f(pb.x) + d.x + rh0*bf2f(h0.x) + rh1*bf2f(h1.x) + rh2*bf2f(h2.x) + rh3*bf2f(h3.x))*rinv;
                float v1 = (bf2f(pb.y) + d.y + rh0*bf2f(h0.y) + rh1*bf2f(h1.y) + rh2*bf2f(h2.y) + rh3*bf2f(h3.y))*rinv;
                float v2 = (bf2f(pb.z) + d.z + rh0*bf2f(h0.z) + rh1*bf2f(h1.z) + rh2*bf2f(h2.z) + rh3*bf2f(h3.z))*rinv;
                float v3 = (bf2f(pb.w) + d.w + rh0*bf2f(h0.w) + rh1*bf2f(h1.w) + rh2*bf2f(h2.w) + rh3*bf2f(h3.w))*rinv;
                v0 = (v0 > 0.f) ? v0 : expm1f(v0);
                v1 = (v1 > 0.f) ? v1 : expm1f(v1);
                v2 = (v2 > 0.f) ? v2 : expm1f(v2);
                v3 = (v3 > 0.f) ? v3 : expm1f(v3);
                float4 r4; r4.x=v0; r4.y=v1; r4.z=v2; r4.w=v3;
                *(float4*)(out + (size_t)n*128 + q*4) = r4;
            }
        }
    }
}

extern "C" void kernel_launch(void* const* d_in, const int* in_sizes, int n_in,
                              void* d_out, int out_size, void* d_ws, size_t ws_size,
                              hipStream_t stream)
{
    const float* input = (const float*)d_in[0];
    const int*   edge  = (const int*)d_in[1];
    const float* emb1  = (const float*)d_in[2];
    const int*   nhop  = (const int*)d_in[3];
    const float* emb2  = (const float*)d_in[4];
    const float* proj  = (const float*)d_in[5];
    const float* W     = (const float*)d_in[6];
    const float* a     = (const float*)d_in[7];
    const float* hw    = (const float*)d_in[8];
    float* out = (float*)d_out;

    const int N  = in_sizes[0] / 128;
    const int E1 = in_sizes[1] / 2;
    const int E2 = in_sizes[3] / 2;
    const int E  = E1 + E2;
    (void)n_in; (void)out_size; (void)ws_size;

    char* wsb = (char*)d_ws;
    size_t off = 0;
    auto alloc = [&](size_t bytes) -> char* {
        char* p = wsb + off;
        off += (bytes + 255) & ~(size_t)255;
        return p;
    };
    u16*   in_bf    = (u16*)alloc((size_t)N*128*2);
    u16*   tbl      = (u16*)alloc((size_t)N*512*2);
    u16*   hsrc_tbl = (u16*)alloc((size_t)N*512*2);
    u16*   semb_bf  = (u16*)alloc((size_t)N*256*2);
    u16*   pout_bf  = (u16*)alloc((size_t)N*128*2);
    u16*   emb_perm = (u16*)alloc((size_t)E*64*2);
    float* ee_perm  = (float*)alloc((size_t)E*4*4);
    int*   csr_tgt  = (int*)alloc((size_t)E*4);
    u16*   M_bf     = (u16*)alloc((size_t)8*16384*2);
    u16*   WcatT_bf = (u16*)alloc((size_t)128*256*2);
    float* asrc     = (float*)alloc(512*4);
    float* atgt     = (float*)alloc(512*4);
    float* arel     = (float*)alloc(256*4);
    float* s_src    = (float*)alloc((size_t)N*4*4);
    float* s_tgt    = (float*)alloc((size_t)N*4*4);
    float* wsoft    = (float*)alloc(4*4);
    float* rowsum4  = (float*)alloc((size_t)N*4*4);
    int*   offsets  = (int*)alloc((size_t)(N+1)*4);
    int*   bsum     = (int*)alloc(64*4);
    int*   boff     = (int*)alloc(64*4);
    const size_t zoff0 = off;
    float* orth_part= (float*)alloc(4*4);
    int*   deg      = (int*)alloc((size_t)N*4);
    int*   cursor   = (int*)alloc((size_t)N*4);
    int*   sdone    = (int*)alloc(4);
    const size_t zoff1 = off;

    hipMemsetAsync(wsb + zoff0, 0, zoff1 - zoff0, stream);

    const int nbScan = (N + 4095) / 4096;
    const int nx = (N + 255) / 256;
    const int nx2 = (N + 127) / 128;
    const int nk0 = ((E > N ? E : N) + 255) / 256;
    int nb4 = (N + 3) / 4; if (nb4 > 3072) nb4 = 3072;

    k1_prep<<<dim3(NHEAD,3,8), dim3(256), 0, stream>>>(proj, W, a, hw, M_bf,
                                                       asrc, atgt, arel, WcatT_bf, wsoft, orth_part);
    k0_nodes<<<dim3(nk0), dim3(256), 0, stream>>>(input, asrc, atgt, edge, nhop,
                                                  in_bf, s_src, s_tgt, deg, N, E1, E2);
    k2_mfma<<<dim3(nx*8), dim3(256), 0, stream>>>(in_bf, M_bf, hsrc_tbl, tbl, N);
    k_scanA<<<dim3(nbScan), dim3(1024), 0, stream>>>(deg, offsets, bsum, boff, sdone, N, nbScan);
    k_fill2<<<dim3((E+255)/256), dim3(256), 0, stream>>>(edge, nhop, emb1, emb2, s_src, s_tgt,
                                                         arel, offsets, boff, cursor,
                                                         csr_tgt, ee_perm, emb_perm, E1, E2);
    k4_gather<<<dim3(nb4), dim3(256), 0, stream>>>(ee_perm, offsets, boff, csr_tgt, emb_perm,
                                                   tbl, wsoft, pout_bf, semb_bf, rowsum4, N);
    k5_gemm<<<dim3(nx2), dim3(256), 0, stream>>>(semb_bf, WcatT_bf, hsrc_tbl, pout_bf,
                                                 rowsum4, wsoft, orth_part, out, N);
}